// Round 8
// baseline (334.884 us; speedup 1.0000x reference)
//
#include <hip/hip_runtime.h>

// GraphSAGE 2-layer. N=50000, E=800000, D_IN=128, D_H=256, D_OUT=128.
//
// R14: consolidation. (a) gemm_fused reverted to the R11 512-thread version
// (best measured: 42.8us; R13's 256-thr wr[4][4] spilled to scratch under
// launch_bounds(256,4): FETCH 13.8->40MB, WRITE 37.5->87MB, 62us).
// (b) scan_blocks+scan_add collapsed into ONE single-block scan dispatch
// (1024 thr x 49 elem, two passes over 200KB, L2-hot) - saves a launch gap.
// Dispatches: prep, hist, scan, fill, gather1, gemm_fused, gather2 = 7.
//
// Pipeline:
//   prep: Wc1/Wc2 bf16 pack | x->bf16 into A1 cols 128..255 | cnt=0 | off[N]=E
//   hist: rank[e] = cnt[dst[e]]++            (E int atomics, rank coalesced)
//   scan: off = exclusive-prefix(cnt)        (single 1024-thr block)
//   fill: csr[off[dst[e]] + rank[e]] = src[e]
//   gather1: A1 cols 0..127 = mean_{s in adj(n)} bf16(x[s])
//   gemm_fused: H=relu(A1@Wc1.T+b1) in LDS; tb=H@W2l.T (bf16);
//               out=H@W2r.T+b2l (fp32)
//   gather2: out[n] += mean_{s in adj(n)} tb[s]
//
// Layer-2 trick: mean(h[src])@W2l.T == mean((h@W2l.T)[src]).

typedef __attribute__((ext_vector_type(8))) short bf16x8;
typedef __attribute__((ext_vector_type(4))) float floatx4;

__device__ inline unsigned short f2b(float f) {
  unsigned int x = __float_as_uint(f);
  unsigned int r = (x + 0x7fffu + ((x >> 16) & 1u)) >> 16;
  return (unsigned short)r;
}
__device__ inline float blo(unsigned int u) { return __uint_as_float(u << 16); }
__device__ inline float bhi(unsigned int u) { return __uint_as_float(u & 0xffff0000u); }

// Fused prep: weight pack, x->bf16 convert, cnt zero, off[N]=E.
__global__ void prep_kernel(const float* __restrict__ x,
                            const float* __restrict__ W1l, const float* __restrict__ W1r,
                            const float* __restrict__ W2l, const float* __restrict__ W2r,
                            unsigned short* __restrict__ Wc1, unsigned short* __restrict__ Wc2,
                            unsigned short* __restrict__ A1,
                            int* __restrict__ cnt, int* __restrict__ off, int N, int E) {
  int i = blockIdx.x * blockDim.x + threadIdx.x;
  if (i < 65536) {
    int j = i >> 8, k = i & 255;
    float v1 = (k < 128) ? W1l[j * 128 + k] : W1r[j * 128 + (k - 128)];
    Wc1[i] = f2b(v1);
    float v2 = (j < 128) ? W2l[j * 256 + k] : W2r[(j - 128) * 256 + k];
    Wc2[i] = f2b(v2);
  }
  if (i < N) cnt[i] = 0;
  if (i == 0) off[N] = E;
  if (i < N * 32) {
    int n = i >> 5, c = (i & 31) * 4;
    float4 v = *(const float4*)(x + (size_t)n * 128 + c);
    uint2 p;
    p.x = (unsigned int)f2b(v.x) | ((unsigned int)f2b(v.y) << 16);
    p.y = (unsigned int)f2b(v.z) | ((unsigned int)f2b(v.w) << 16);
    *(uint2*)(A1 + (size_t)n * 256 + 128 + c) = p;
  }
}

// Histogram + per-edge rank capture (4 edges/thread, vectorized loads).
__global__ void hist_kernel(const int* __restrict__ dst, int* __restrict__ cnt,
                            int* __restrict__ rank, int E) {
  int i = blockIdx.x * blockDim.x + threadIdx.x;
  int e = i * 4;
  if (e + 3 < E) {
    int4 d = *(const int4*)(dst + e);
    int4 r;
    r.x = atomicAdd(&cnt[d.x], 1);
    r.y = atomicAdd(&cnt[d.y], 1);
    r.z = atomicAdd(&cnt[d.z], 1);
    r.w = atomicAdd(&cnt[d.w], 1);
    *(int4*)(rank + e) = r;
  } else {
    for (; e < E; e++) rank[e] = atomicAdd(&cnt[dst[e]], 1);
  }
}

// Single-block exclusive scan: 1024 threads, CH elems/thread, two passes.
__global__ __launch_bounds__(1024) void scan_kernel(const int* __restrict__ cnt,
                                                    int* __restrict__ off, int N) {
  __shared__ int wsum[16];
  __shared__ int wbase[16];
  const int tid = threadIdx.x;
  const int lane = tid & 63;
  const int wv = tid >> 6;
  const int CH = (N + 1023) / 1024;  // 49
  const int lo = tid * CH;
  const int hi = min(N, lo + CH);
  // Pass 1: per-thread sum.
  int s = 0;
  for (int i = lo; i < hi; i++) s += cnt[i];
  const int mysum = s;
  // Wave inclusive scan.
#pragma unroll
  for (int o = 1; o < 64; o <<= 1) {
    int t = __shfl_up(s, o, 64);
    if (lane >= o) s += t;
  }
  if (lane == 63) wsum[wv] = s;
  __syncthreads();
  if (tid < 16) {
    int ws = wsum[tid];
#pragma unroll
    for (int o = 1; o < 16; o <<= 1) {
      int t = __shfl_up(ws, o, 16);
      if ((tid & 15) >= o) ws += t;
    }
    wbase[tid] = ws;
  }
  __syncthreads();
  // Exclusive base for this thread.
  int base = (wv ? wbase[wv - 1] : 0) + s - mysum;
  // Pass 2: write exclusive prefix (cnt re-read, L2-hot).
  for (int i = lo; i < hi; i++) {
    off[i] = base;
    base += cnt[i];
  }
}

// Atomic-free fill: plain scattered stores, 4 edges/thread.
__global__ void fill_kernel(const int* __restrict__ src, const int* __restrict__ dst,
                            const int* __restrict__ rank, const int* __restrict__ off,
                            int* __restrict__ csr, int E) {
  int i = blockIdx.x * blockDim.x + threadIdx.x;
  int e = i * 4;
  if (e + 3 < E) {
    int4 d = *(const int4*)(dst + e);
    int4 r = *(const int4*)(rank + e);
    int4 s = *(const int4*)(src + e);
    csr[off[d.x] + r.x] = s.x;
    csr[off[d.y] + r.y] = s.y;
    csr[off[d.z] + r.z] = s.z;
    csr[off[d.w] + r.w] = s.w;
  } else {
    for (; e < E; e++) csr[off[dst[e]] + rank[e]] = src[e];
  }
}

// Gather-mean, one wave per node, 64 lanes per edge-row. Lane l owns columns
// 2l,2l+1 (one dword of the 256B row): no cross-lane reduction; coalesced
// 1-dword/lane loads. 8-edge unroll -> 8 row-loads outstanding; 2-edge
// mid-tail. Edge ids via lane-parallel csr read + __shfl broadcast.
__global__ void gather1_kernel(const unsigned short* __restrict__ feat,
                               const int* __restrict__ csr, const int* __restrict__ off,
                               unsigned short* __restrict__ ob, int N) {
  int wid = (blockIdx.x * blockDim.x + threadIdx.x) >> 6;
  if (wid >= N) return;
  const int lane = threadIdx.x & 63;
  const int s0 = off[wid], s1 = off[wid + 1];
  float a0 = 0.f, a1 = 0.f;
  for (int base = s0; base < s1; base += 64) {
    const int cnt = min(64, s1 - base);
    int my = (lane < cnt) ? csr[base + lane] : 0;
    int k = 0;
    for (; k + 8 <= cnt; k += 8) {
      int i0 = __shfl(my, k);
      int i1 = __shfl(my, k + 1);
      int i2 = __shfl(my, k + 2);
      int i3 = __shfl(my, k + 3);
      int i4 = __shfl(my, k + 4);
      int i5 = __shfl(my, k + 5);
      int i6 = __shfl(my, k + 6);
      int i7 = __shfl(my, k + 7);
      unsigned u0 = ((const unsigned*)(feat + (size_t)i0 * 256))[lane];
      unsigned u1 = ((const unsigned*)(feat + (size_t)i1 * 256))[lane];
      unsigned u2 = ((const unsigned*)(feat + (size_t)i2 * 256))[lane];
      unsigned u3 = ((const unsigned*)(feat + (size_t)i3 * 256))[lane];
      unsigned u4 = ((const unsigned*)(feat + (size_t)i4 * 256))[lane];
      unsigned u5 = ((const unsigned*)(feat + (size_t)i5 * 256))[lane];
      unsigned u6 = ((const unsigned*)(feat + (size_t)i6 * 256))[lane];
      unsigned u7 = ((const unsigned*)(feat + (size_t)i7 * 256))[lane];
      a0 += blo(u0); a1 += bhi(u0);
      a0 += blo(u1); a1 += bhi(u1);
      a0 += blo(u2); a1 += bhi(u2);
      a0 += blo(u3); a1 += bhi(u3);
      a0 += blo(u4); a1 += bhi(u4);
      a0 += blo(u5); a1 += bhi(u5);
      a0 += blo(u6); a1 += bhi(u6);
      a0 += blo(u7); a1 += bhi(u7);
    }
    for (; k + 2 <= cnt; k += 2) {
      int i0 = __shfl(my, k);
      int i1 = __shfl(my, k + 1);
      unsigned u0 = ((const unsigned*)(feat + (size_t)i0 * 256))[lane];
      unsigned u1 = ((const unsigned*)(feat + (size_t)i1 * 256))[lane];
      a0 += blo(u0); a1 += bhi(u0);
      a0 += blo(u1); a1 += bhi(u1);
    }
    if (k < cnt) {
      int i0 = __shfl(my, k);
      unsigned u0 = ((const unsigned*)(feat + (size_t)i0 * 256))[lane];
      a0 += blo(u0); a1 += bhi(u0);
    }
  }
  const float inv = 1.0f / fmaxf((float)(s1 - s0), 1.0f);
  unsigned p = (unsigned)f2b(a0 * inv) | ((unsigned)f2b(a1 * inv) << 16);
  ((unsigned*)(ob + (size_t)wid * 256))[lane] = p;
}

// Same structure; feat (tb) stride 128 ushorts; accumulate into fp32 out.
// out row prefetched BEFORE the loop (overlaps gather latency).
__global__ void gather2_kernel(const unsigned short* __restrict__ t,
                               const int* __restrict__ csr, const int* __restrict__ off,
                               float* __restrict__ out, int N) {
  int wid = (blockIdx.x * blockDim.x + threadIdx.x) >> 6;
  if (wid >= N) return;
  const int lane = threadIdx.x & 63;
  const int s0 = off[wid], s1 = off[wid + 1];
  float2* op = (float2*)(out + (size_t)wid * 128) + lane;
  float2 r = *op;  // prefetch RMW operand early
  float a0 = 0.f, a1 = 0.f;
  for (int base = s0; base < s1; base += 64) {
    const int cnt = min(64, s1 - base);
    int my = (lane < cnt) ? csr[base + lane] : 0;
    int k = 0;
    for (; k + 8 <= cnt; k += 8) {
      int i0 = __shfl(my, k);
      int i1 = __shfl(my, k + 1);
      int i2 = __shfl(my, k + 2);
      int i3 = __shfl(my, k + 3);
      int i4 = __shfl(my, k + 4);
      int i5 = __shfl(my, k + 5);
      int i6 = __shfl(my, k + 6);
      int i7 = __shfl(my, k + 7);
      unsigned u0 = ((const unsigned*)(t + (size_t)i0 * 128))[lane];
      unsigned u1 = ((const unsigned*)(t + (size_t)i1 * 128))[lane];
      unsigned u2 = ((const unsigned*)(t + (size_t)i2 * 128))[lane];
      unsigned u3 = ((const unsigned*)(t + (size_t)i3 * 128))[lane];
      unsigned u4 = ((const unsigned*)(t + (size_t)i4 * 128))[lane];
      unsigned u5 = ((const unsigned*)(t + (size_t)i5 * 128))[lane];
      unsigned u6 = ((const unsigned*)(t + (size_t)i6 * 128))[lane];
      unsigned u7 = ((const unsigned*)(t + (size_t)i7 * 128))[lane];
      a0 += blo(u0); a1 += bhi(u0);
      a0 += blo(u1); a1 += bhi(u1);
      a0 += blo(u2); a1 += bhi(u2);
      a0 += blo(u3); a1 += bhi(u3);
      a0 += blo(u4); a1 += bhi(u4);
      a0 += blo(u5); a1 += bhi(u5);
      a0 += blo(u6); a1 += bhi(u6);
      a0 += blo(u7); a1 += bhi(u7);
    }
    for (; k + 2 <= cnt; k += 2) {
      int i0 = __shfl(my, k);
      int i1 = __shfl(my, k + 1);
      unsigned u0 = ((const unsigned*)(t + (size_t)i0 * 128))[lane];
      unsigned u1 = ((const unsigned*)(t + (size_t)i1 * 128))[lane];
      a0 += blo(u0); a1 += bhi(u0);
      a0 += blo(u1); a1 += bhi(u1);
    }
    if (k < cnt) {
      int i0 = __shfl(my, k);
      unsigned u0 = ((const unsigned*)(t + (size_t)i0 * 128))[lane];
      a0 += blo(u0); a1 += bhi(u0);
    }
  }
  const float inv = 1.0f / fmaxf((float)(s1 - s0), 1.0f);
  r.x += a0 * inv;
  r.y += a1 * inv;
  *op = r;
}

// Fused 2-layer bf16 MFMA GEMM (R11 version, best measured). 512 thr = 8
// waves; wave w owns rows 0..63 x cols [w*32,w*32+32). Phase A: wr=W1 frags
// (wr[2][8]=64 VGPR, loaded once from L2), A-tile staged to LDS (LDA=264,
// conflict-free b128); H=relu(acc+b1) -> Hs (LDS). Reload wr=W2 frags;
// phase B: acc=Hs@W2.T; waves 0-3: tb=bf16(acc); waves 4-7: out=acc+b2.
// 2 barriers; no global loads inside MFMA loops.
__global__ __launch_bounds__(512, 4)
void gemm_fused(const unsigned short* __restrict__ A, const unsigned short* __restrict__ Wc1,
                const unsigned short* __restrict__ Wc2,
                const float* __restrict__ b1, const float* __restrict__ b2,
                unsigned short* __restrict__ tb, float* __restrict__ out, int M) {
  constexpr int LDA = 264;
  __shared__ __align__(16) unsigned short As[64 * LDA];
  __shared__ __align__(16) unsigned short Hs[64 * LDA];
  const int t = threadIdx.x;
  const int lane = t & 63;
  const int wave = t >> 6;
  const int wn = wave * 32;
  const int l15 = lane & 15;
  const int quad = lane >> 4;
  const int m_blk = blockIdx.x * 64;

  // Resident W1 fragments: j = wn + nt*16 + l15, k = c*32 + quad*8.
  bf16x8 wr[2][8];
#pragma unroll
  for (int nt = 0; nt < 2; nt++) {
    const unsigned short* wp = Wc1 + (size_t)(wn + nt * 16 + l15) * 256 + quad * 8;
#pragma unroll
    for (int c = 0; c < 8; c++) wr[nt][c] = *(const bf16x8*)(wp + c * 32);
  }
  const float bv0 = b1[wn + l15];
  const float bv1 = b1[wn + 16 + l15];

  // Stage A tile (64 rows x 256 k = 32 KB).
#pragma unroll
  for (int i = 0; i < 4; i++) {
    int idx = t + 512 * i;
    int row = idx >> 5, cc = (idx & 31) * 8;
    int ar = m_blk + row;
    if (ar >= M) ar = M - 1;
    *(uint4*)(As + row * LDA + cc) = *(const uint4*)(A + (size_t)ar * 256 + cc);
  }
  __syncthreads();

  // ---- Phase A: acc = A @ Wc1.T ----
  floatx4 acc[4][2] = {};
#pragma unroll
  for (int c = 0; c < 8; c++) {
    bf16x8 af[4];
#pragma unroll
    for (int mt = 0; mt < 4; mt++)
      af[mt] = *(const bf16x8*)(As + (mt * 16 + l15) * LDA + c * 32 + quad * 8);
#pragma unroll
    for (int mt = 0; mt < 4; mt++) {
      acc[mt][0] = __builtin_amdgcn_mfma_f32_16x16x32_bf16(af[mt], wr[0][c], acc[mt][0], 0, 0, 0);
      acc[mt][1] = __builtin_amdgcn_mfma_f32_16x16x32_bf16(af[mt], wr[1][c], acc[mt][1], 0, 0, 0);
    }
  }

  // Epilogue A: H = relu(acc + b1) into Hs.
#pragma unroll
  for (int mt = 0; mt < 4; mt++) {
#pragma unroll
    for (int nt = 0; nt < 2; nt++) {
      const int jl = wn + nt * 16 + l15;
      const float bv = nt ? bv1 : bv0;
#pragma unroll
      for (int r = 0; r < 4; r++) {
        const int row = mt * 16 + quad * 4 + r;
        Hs[row * LDA + jl] = f2b(fmaxf(acc[mt][nt][r] + bv, 0.f));
      }
    }
  }

  // Reload wr with W2 fragments (independent of Hs; overlaps other waves'
  // epilogue work before the barrier).
#pragma unroll
  for (int nt = 0; nt < 2; nt++) {
    const unsigned short* wp = Wc2 + (size_t)(wn + nt * 16 + l15) * 256 + quad * 8;
#pragma unroll
    for (int c = 0; c < 8; c++) wr[nt][c] = *(const bf16x8*)(wp + c * 32);
  }
  const float cv0 = (wn >= 128) ? b2[wn - 128 + l15] : 0.f;
  const float cv1 = (wn >= 128) ? b2[wn - 112 + l15] : 0.f;
  __syncthreads();

  // ---- Phase B: acc = Hs @ Wc2.T ----
#pragma unroll
  for (int mt = 0; mt < 4; mt++) {
    acc[mt][0] = (floatx4){0.f, 0.f, 0.f, 0.f};
    acc[mt][1] = (floatx4){0.f, 0.f, 0.f, 0.f};
  }
#pragma unroll
  for (int c = 0; c < 8; c++) {
    bf16x8 af[4];
#pragma unroll
    for (int mt = 0; mt < 4; mt++)
      af[mt] = *(const bf16x8*)(Hs + (mt * 16 + l15) * LDA + c * 32 + quad * 8);
#pragma unroll
    for (int mt = 0; mt < 4; mt++) {
      acc[mt][0] = __builtin_amdgcn_mfma_f32_16x16x32_bf16(af[mt], wr[0][c], acc[mt][0], 0, 0, 0);
      acc[mt][1] = __builtin_amdgcn_mfma_f32_16x16x32_bf16(af[mt], wr[1][c], acc[mt][1], 0, 0, 0);
    }
  }

  // Epilogue B: waves 0-3 (j<128) -> tb bf16; waves 4-7 -> out fp32 + bias.
#pragma unroll
  for (int mt = 0; mt < 4; mt++) {
#pragma unroll
    for (int nt = 0; nt < 2; nt++) {
      const int j = wn + nt * 16 + l15;
      const float bv = nt ? cv1 : cv0;
#pragma unroll
      for (int r = 0; r < 4; r++) {
        const int node = m_blk + mt * 16 + quad * 4 + r;
        if (node >= M) continue;
        const float v = acc[mt][nt][r];
        if (j < 128) {
          tb[(size_t)node * 128 + j] = f2b(v);
        } else {
          out[(size_t)node * 128 + (j - 128)] = v + bv;
        }
      }
    }
  }
}

extern "C" void kernel_launch(void* const* d_in, const int* in_sizes, int n_in,
                              void* d_out, int out_size, void* d_ws, size_t ws_size,
                              hipStream_t stream) {
  const float* x   = (const float*)d_in[0];
  const int*  eidx = (const int*)d_in[1];
  const float* W1l = (const float*)d_in[2];
  const float* b1l = (const float*)d_in[3];
  const float* W1r = (const float*)d_in[4];
  const float* W2l = (const float*)d_in[5];
  const float* b2l = (const float*)d_in[6];
  const float* W2r = (const float*)d_in[7];
  float* out = (float*)d_out;

  const int N = in_sizes[0] / 128;
  const int E = in_sizes[1] / 2;
  const int* src = eidx;
  const int* dst = eidx + E;

  int* cnt  = (int*)d_ws;          // [N]
  int* off  = cnt + N;             // [N+1]
  int* bsum = off + N + 1;         // [64] (unused, layout kept)
  int* rank = bsum + 64;           // [E]
  int* csr  = rank + E;            // [E]
  size_t ioff = ((size_t)(N + N + 1 + 64 + 2 * E) * 4 + 15) & ~(size_t)15;
  unsigned short* A1  = (unsigned short*)((char*)d_ws + ioff);  // [N][256]
  unsigned short* tb  = A1 + (size_t)N * 256;                   // [N][128]
  unsigned short* Wc1 = tb + (size_t)N * 128;                   // [256][256]
  unsigned short* Wc2 = Wc1 + 65536;                            // [256][256]

  prep_kernel<<<(N * 32 + 255) / 256, 256, 0, stream>>>(x, W1l, W1r, W2l, W2r,
                                                        Wc1, Wc2, A1, cnt, off, N, E);
  hist_kernel<<<(E / 4 + 255) / 256, 256, 0, stream>>>(dst, cnt, rank, E);
  scan_kernel<<<1, 1024, 0, stream>>>(cnt, off, N);
  fill_kernel<<<(E / 4 + 255) / 256, 256, 0, stream>>>(src, dst, rank, off, csr, E);

  const int gblocks = (N + 3) / 4;  // 1 wave (64 lanes) per node
  gather1_kernel<<<gblocks, 256, 0, stream>>>(A1 + 128, csr, off, A1, N);

  gemm_fused<<<(N + 63) / 64, 512, 0, stream>>>(A1, Wc1, Wc2, b1l, b2l, tb, out, N);

  gather2_kernel<<<gblocks, 256, 0, stream>>>(tb, csr, off, out, N);
}

// Round 9
// 265.437 us; speedup vs baseline: 1.2616x; 1.2616x over previous
//
#include <hip/hip_runtime.h>

// GraphSAGE 2-layer. N=50000, E=800000, D_IN=128, D_H=256, D_OUT=128.
//
// R15: revert R14's single-block scan (measured 77.8us: ONE block = one CU,
// 2x49 serial dependent L2 loads/thread, zero TLP -> pure exposed latency).
// Back to the R11 hierarchical scan (scan_blocks 49x1024 + scan_add, ~5us).
// Everything else = R14 (gemm_fused is the best-measured R11 512-thr version).
//
// Pipeline:
//   prep: Wc1/Wc2 bf16 pack | x->bf16 into A1 cols 128..255 | cnt=0 | off[N]=E
//   hist: rank[e] = cnt[dst[e]]++            (E int atomics, rank coalesced)
//   scan_blocks / scan_add: exclusive scan -> off
//   fill: csr[off[dst[e]] + rank[e]] = src[e]
//   gather1: A1 cols 0..127 = mean_{s in adj(n)} bf16(x[s])
//   gemm_fused: H=relu(A1@Wc1.T+b1) in LDS; tb=H@W2l.T (bf16);
//               out=H@W2r.T+b2l (fp32)
//   gather2: out[n] += mean_{s in adj(n)} tb[s]
//
// Layer-2 trick: mean(h[src])@W2l.T == mean((h@W2l.T)[src]).

typedef __attribute__((ext_vector_type(8))) short bf16x8;
typedef __attribute__((ext_vector_type(4))) float floatx4;

__device__ inline unsigned short f2b(float f) {
  unsigned int x = __float_as_uint(f);
  unsigned int r = (x + 0x7fffu + ((x >> 16) & 1u)) >> 16;
  return (unsigned short)r;
}
__device__ inline float blo(unsigned int u) { return __uint_as_float(u << 16); }
__device__ inline float bhi(unsigned int u) { return __uint_as_float(u & 0xffff0000u); }

// Fused prep: weight pack, x->bf16 convert, cnt zero, off[N]=E.
__global__ void prep_kernel(const float* __restrict__ x,
                            const float* __restrict__ W1l, const float* __restrict__ W1r,
                            const float* __restrict__ W2l, const float* __restrict__ W2r,
                            unsigned short* __restrict__ Wc1, unsigned short* __restrict__ Wc2,
                            unsigned short* __restrict__ A1,
                            int* __restrict__ cnt, int* __restrict__ off, int N, int E) {
  int i = blockIdx.x * blockDim.x + threadIdx.x;
  if (i < 65536) {
    int j = i >> 8, k = i & 255;
    float v1 = (k < 128) ? W1l[j * 128 + k] : W1r[j * 128 + (k - 128)];
    Wc1[i] = f2b(v1);
    float v2 = (j < 128) ? W2l[j * 256 + k] : W2r[(j - 128) * 256 + k];
    Wc2[i] = f2b(v2);
  }
  if (i < N) cnt[i] = 0;
  if (i == 0) off[N] = E;
  if (i < N * 32) {
    int n = i >> 5, c = (i & 31) * 4;
    float4 v = *(const float4*)(x + (size_t)n * 128 + c);
    uint2 p;
    p.x = (unsigned int)f2b(v.x) | ((unsigned int)f2b(v.y) << 16);
    p.y = (unsigned int)f2b(v.z) | ((unsigned int)f2b(v.w) << 16);
    *(uint2*)(A1 + (size_t)n * 256 + 128 + c) = p;
  }
}

// Histogram + per-edge rank capture (4 edges/thread, vectorized loads).
__global__ void hist_kernel(const int* __restrict__ dst, int* __restrict__ cnt,
                            int* __restrict__ rank, int E) {
  int i = blockIdx.x * blockDim.x + threadIdx.x;
  int e = i * 4;
  if (e + 3 < E) {
    int4 d = *(const int4*)(dst + e);
    int4 r;
    r.x = atomicAdd(&cnt[d.x], 1);
    r.y = atomicAdd(&cnt[d.y], 1);
    r.z = atomicAdd(&cnt[d.z], 1);
    r.w = atomicAdd(&cnt[d.w], 1);
    *(int4*)(rank + e) = r;
  } else {
    for (; e < E; e++) rank[e] = atomicAdd(&cnt[dst[e]], 1);
  }
}

// Per-1024-block exclusive scan; block total -> bsum[b].
__global__ __launch_bounds__(1024) void scan_blocks_kernel(const int* __restrict__ cnt,
                                                           int* __restrict__ off,
                                                           int* __restrict__ bsum, int N) {
  __shared__ int wsum[16];
  __shared__ int wincl[16];
  const int tid = threadIdx.x;
  const int lane = tid & 63;
  const int wv = tid >> 6;
  const int i = blockIdx.x * 1024 + tid;
  const int v = (i < N) ? cnt[i] : 0;
  int s = v;
#pragma unroll
  for (int o = 1; o < 64; o <<= 1) {
    int t = __shfl_up(s, o, 64);
    if (lane >= o) s += t;
  }
  if (lane == 63) wsum[wv] = s;
  __syncthreads();
  if (tid < 16) {
    int ws = wsum[tid];
#pragma unroll
    for (int o = 1; o < 16; o <<= 1) {
      int t = __shfl_up(ws, o, 16);
      if ((tid & 15) >= o) ws += t;
    }
    wincl[tid] = ws;
  }
  __syncthreads();
  const int wo = wv ? wincl[wv - 1] : 0;
  if (i < N) off[i] = wo + s - v;
  if (tid == 1023) bsum[blockIdx.x] = wo + s;
}

// Add block offsets (block-sum scan inlined: <=64 sums, wave 0).
__global__ __launch_bounds__(1024) void scan_add_kernel(int* __restrict__ off,
                                                        const int* __restrict__ bsum, int N, int SB) {
  __shared__ int bofs[64];
  const int tid = threadIdx.x;
  if (tid < 64) {
    int v = (tid < SB) ? bsum[tid] : 0;
    int s = v;
#pragma unroll
    for (int o = 1; o < 64; o <<= 1) {
      int t = __shfl_up(s, o, 64);
      if (tid >= o) s += t;
    }
    bofs[tid] = s - v;
  }
  __syncthreads();
  int i = blockIdx.x * 1024 + tid;
  if (i < N) off[i] = off[i] + bofs[blockIdx.x];
}

// Atomic-free fill: plain scattered stores, 4 edges/thread.
__global__ void fill_kernel(const int* __restrict__ src, const int* __restrict__ dst,
                            const int* __restrict__ rank, const int* __restrict__ off,
                            int* __restrict__ csr, int E) {
  int i = blockIdx.x * blockDim.x + threadIdx.x;
  int e = i * 4;
  if (e + 3 < E) {
    int4 d = *(const int4*)(dst + e);
    int4 r = *(const int4*)(rank + e);
    int4 s = *(const int4*)(src + e);
    csr[off[d.x] + r.x] = s.x;
    csr[off[d.y] + r.y] = s.y;
    csr[off[d.z] + r.z] = s.z;
    csr[off[d.w] + r.w] = s.w;
  } else {
    for (; e < E; e++) csr[off[dst[e]] + rank[e]] = src[e];
  }
}

// Gather-mean, one wave per node, 64 lanes per edge-row. Lane l owns columns
// 2l,2l+1 (one dword of the 256B row): no cross-lane reduction; coalesced
// 1-dword/lane loads. 8-edge unroll -> 8 row-loads outstanding; 2-edge
// mid-tail. Edge ids via lane-parallel csr read + __shfl broadcast.
__global__ void gather1_kernel(const unsigned short* __restrict__ feat,
                               const int* __restrict__ csr, const int* __restrict__ off,
                               unsigned short* __restrict__ ob, int N) {
  int wid = (blockIdx.x * blockDim.x + threadIdx.x) >> 6;
  if (wid >= N) return;
  const int lane = threadIdx.x & 63;
  const int s0 = off[wid], s1 = off[wid + 1];
  float a0 = 0.f, a1 = 0.f;
  for (int base = s0; base < s1; base += 64) {
    const int cnt = min(64, s1 - base);
    int my = (lane < cnt) ? csr[base + lane] : 0;
    int k = 0;
    for (; k + 8 <= cnt; k += 8) {
      int i0 = __shfl(my, k);
      int i1 = __shfl(my, k + 1);
      int i2 = __shfl(my, k + 2);
      int i3 = __shfl(my, k + 3);
      int i4 = __shfl(my, k + 4);
      int i5 = __shfl(my, k + 5);
      int i6 = __shfl(my, k + 6);
      int i7 = __shfl(my, k + 7);
      unsigned u0 = ((const unsigned*)(feat + (size_t)i0 * 256))[lane];
      unsigned u1 = ((const unsigned*)(feat + (size_t)i1 * 256))[lane];
      unsigned u2 = ((const unsigned*)(feat + (size_t)i2 * 256))[lane];
      unsigned u3 = ((const unsigned*)(feat + (size_t)i3 * 256))[lane];
      unsigned u4 = ((const unsigned*)(feat + (size_t)i4 * 256))[lane];
      unsigned u5 = ((const unsigned*)(feat + (size_t)i5 * 256))[lane];
      unsigned u6 = ((const unsigned*)(feat + (size_t)i6 * 256))[lane];
      unsigned u7 = ((const unsigned*)(feat + (size_t)i7 * 256))[lane];
      a0 += blo(u0); a1 += bhi(u0);
      a0 += blo(u1); a1 += bhi(u1);
      a0 += blo(u2); a1 += bhi(u2);
      a0 += blo(u3); a1 += bhi(u3);
      a0 += blo(u4); a1 += bhi(u4);
      a0 += blo(u5); a1 += bhi(u5);
      a0 += blo(u6); a1 += bhi(u6);
      a0 += blo(u7); a1 += bhi(u7);
    }
    for (; k + 2 <= cnt; k += 2) {
      int i0 = __shfl(my, k);
      int i1 = __shfl(my, k + 1);
      unsigned u0 = ((const unsigned*)(feat + (size_t)i0 * 256))[lane];
      unsigned u1 = ((const unsigned*)(feat + (size_t)i1 * 256))[lane];
      a0 += blo(u0); a1 += bhi(u0);
      a0 += blo(u1); a1 += bhi(u1);
    }
    if (k < cnt) {
      int i0 = __shfl(my, k);
      unsigned u0 = ((const unsigned*)(feat + (size_t)i0 * 256))[lane];
      a0 += blo(u0); a1 += bhi(u0);
    }
  }
  const float inv = 1.0f / fmaxf((float)(s1 - s0), 1.0f);
  unsigned p = (unsigned)f2b(a0 * inv) | ((unsigned)f2b(a1 * inv) << 16);
  ((unsigned*)(ob + (size_t)wid * 256))[lane] = p;
}

// Same structure; feat (tb) stride 128 ushorts; accumulate into fp32 out.
// out row prefetched BEFORE the loop (overlaps gather latency).
__global__ void gather2_kernel(const unsigned short* __restrict__ t,
                               const int* __restrict__ csr, const int* __restrict__ off,
                               float* __restrict__ out, int N) {
  int wid = (blockIdx.x * blockDim.x + threadIdx.x) >> 6;
  if (wid >= N) return;
  const int lane = threadIdx.x & 63;
  const int s0 = off[wid], s1 = off[wid + 1];
  float2* op = (float2*)(out + (size_t)wid * 128) + lane;
  float2 r = *op;  // prefetch RMW operand early
  float a0 = 0.f, a1 = 0.f;
  for (int base = s0; base < s1; base += 64) {
    const int cnt = min(64, s1 - base);
    int my = (lane < cnt) ? csr[base + lane] : 0;
    int k = 0;
    for (; k + 8 <= cnt; k += 8) {
      int i0 = __shfl(my, k);
      int i1 = __shfl(my, k + 1);
      int i2 = __shfl(my, k + 2);
      int i3 = __shfl(my, k + 3);
      int i4 = __shfl(my, k + 4);
      int i5 = __shfl(my, k + 5);
      int i6 = __shfl(my, k + 6);
      int i7 = __shfl(my, k + 7);
      unsigned u0 = ((const unsigned*)(t + (size_t)i0 * 128))[lane];
      unsigned u1 = ((const unsigned*)(t + (size_t)i1 * 128))[lane];
      unsigned u2 = ((const unsigned*)(t + (size_t)i2 * 128))[lane];
      unsigned u3 = ((const unsigned*)(t + (size_t)i3 * 128))[lane];
      unsigned u4 = ((const unsigned*)(t + (size_t)i4 * 128))[lane];
      unsigned u5 = ((const unsigned*)(t + (size_t)i5 * 128))[lane];
      unsigned u6 = ((const unsigned*)(t + (size_t)i6 * 128))[lane];
      unsigned u7 = ((const unsigned*)(t + (size_t)i7 * 128))[lane];
      a0 += blo(u0); a1 += bhi(u0);
      a0 += blo(u1); a1 += bhi(u1);
      a0 += blo(u2); a1 += bhi(u2);
      a0 += blo(u3); a1 += bhi(u3);
      a0 += blo(u4); a1 += bhi(u4);
      a0 += blo(u5); a1 += bhi(u5);
      a0 += blo(u6); a1 += bhi(u6);
      a0 += blo(u7); a1 += bhi(u7);
    }
    for (; k + 2 <= cnt; k += 2) {
      int i0 = __shfl(my, k);
      int i1 = __shfl(my, k + 1);
      unsigned u0 = ((const unsigned*)(t + (size_t)i0 * 128))[lane];
      unsigned u1 = ((const unsigned*)(t + (size_t)i1 * 128))[lane];
      a0 += blo(u0); a1 += bhi(u0);
      a0 += blo(u1); a1 += bhi(u1);
    }
    if (k < cnt) {
      int i0 = __shfl(my, k);
      unsigned u0 = ((const unsigned*)(t + (size_t)i0 * 128))[lane];
      a0 += blo(u0); a1 += bhi(u0);
    }
  }
  const float inv = 1.0f / fmaxf((float)(s1 - s0), 1.0f);
  r.x += a0 * inv;
  r.y += a1 * inv;
  *op = r;
}

// Fused 2-layer bf16 MFMA GEMM (R11 version, best measured). 512 thr = 8
// waves; wave w owns rows 0..63 x cols [w*32,w*32+32). Phase A: wr=W1 frags
// (wr[2][8]=64 VGPR, loaded once from L2), A-tile staged to LDS (LDA=264,
// conflict-free b128); H=relu(acc+b1) -> Hs (LDS). Reload wr=W2 frags;
// phase B: acc=Hs@W2.T; waves 0-3: tb=bf16(acc); waves 4-7: out=acc+b2.
// 2 barriers; no global loads inside MFMA loops.
__global__ __launch_bounds__(512, 4)
void gemm_fused(const unsigned short* __restrict__ A, const unsigned short* __restrict__ Wc1,
                const unsigned short* __restrict__ Wc2,
                const float* __restrict__ b1, const float* __restrict__ b2,
                unsigned short* __restrict__ tb, float* __restrict__ out, int M) {
  constexpr int LDA = 264;
  __shared__ __align__(16) unsigned short As[64 * LDA];
  __shared__ __align__(16) unsigned short Hs[64 * LDA];
  const int t = threadIdx.x;
  const int lane = t & 63;
  const int wave = t >> 6;
  const int wn = wave * 32;
  const int l15 = lane & 15;
  const int quad = lane >> 4;
  const int m_blk = blockIdx.x * 64;

  // Resident W1 fragments: j = wn + nt*16 + l15, k = c*32 + quad*8.
  bf16x8 wr[2][8];
#pragma unroll
  for (int nt = 0; nt < 2; nt++) {
    const unsigned short* wp = Wc1 + (size_t)(wn + nt * 16 + l15) * 256 + quad * 8;
#pragma unroll
    for (int c = 0; c < 8; c++) wr[nt][c] = *(const bf16x8*)(wp + c * 32);
  }
  const float bv0 = b1[wn + l15];
  const float bv1 = b1[wn + 16 + l15];

  // Stage A tile (64 rows x 256 k = 32 KB).
#pragma unroll
  for (int i = 0; i < 4; i++) {
    int idx = t + 512 * i;
    int row = idx >> 5, cc = (idx & 31) * 8;
    int ar = m_blk + row;
    if (ar >= M) ar = M - 1;
    *(uint4*)(As + row * LDA + cc) = *(const uint4*)(A + (size_t)ar * 256 + cc);
  }
  __syncthreads();

  // ---- Phase A: acc = A @ Wc1.T ----
  floatx4 acc[4][2] = {};
#pragma unroll
  for (int c = 0; c < 8; c++) {
    bf16x8 af[4];
#pragma unroll
    for (int mt = 0; mt < 4; mt++)
      af[mt] = *(const bf16x8*)(As + (mt * 16 + l15) * LDA + c * 32 + quad * 8);
#pragma unroll
    for (int mt = 0; mt < 4; mt++) {
      acc[mt][0] = __builtin_amdgcn_mfma_f32_16x16x32_bf16(af[mt], wr[0][c], acc[mt][0], 0, 0, 0);
      acc[mt][1] = __builtin_amdgcn_mfma_f32_16x16x32_bf16(af[mt], wr[1][c], acc[mt][1], 0, 0, 0);
    }
  }

  // Epilogue A: H = relu(acc + b1) into Hs.
#pragma unroll
  for (int mt = 0; mt < 4; mt++) {
#pragma unroll
    for (int nt = 0; nt < 2; nt++) {
      const int jl = wn + nt * 16 + l15;
      const float bv = nt ? bv1 : bv0;
#pragma unroll
      for (int r = 0; r < 4; r++) {
        const int row = mt * 16 + quad * 4 + r;
        Hs[row * LDA + jl] = f2b(fmaxf(acc[mt][nt][r] + bv, 0.f));
      }
    }
  }

  // Reload wr with W2 fragments (independent of Hs; overlaps other waves'
  // epilogue work before the barrier).
#pragma unroll
  for (int nt = 0; nt < 2; nt++) {
    const unsigned short* wp = Wc2 + (size_t)(wn + nt * 16 + l15) * 256 + quad * 8;
#pragma unroll
    for (int c = 0; c < 8; c++) wr[nt][c] = *(const bf16x8*)(wp + c * 32);
  }
  const float cv0 = (wn >= 128) ? b2[wn - 128 + l15] : 0.f;
  const float cv1 = (wn >= 128) ? b2[wn - 112 + l15] : 0.f;
  __syncthreads();

  // ---- Phase B: acc = Hs @ Wc2.T ----
#pragma unroll
  for (int mt = 0; mt < 4; mt++) {
    acc[mt][0] = (floatx4){0.f, 0.f, 0.f, 0.f};
    acc[mt][1] = (floatx4){0.f, 0.f, 0.f, 0.f};
  }
#pragma unroll
  for (int c = 0; c < 8; c++) {
    bf16x8 af[4];
#pragma unroll
    for (int mt = 0; mt < 4; mt++)
      af[mt] = *(const bf16x8*)(Hs + (mt * 16 + l15) * LDA + c * 32 + quad * 8);
#pragma unroll
    for (int mt = 0; mt < 4; mt++) {
      acc[mt][0] = __builtin_amdgcn_mfma_f32_16x16x32_bf16(af[mt], wr[0][c], acc[mt][0], 0, 0, 0);
      acc[mt][1] = __builtin_amdgcn_mfma_f32_16x16x32_bf16(af[mt], wr[1][c], acc[mt][1], 0, 0, 0);
    }
  }

  // Epilogue B: waves 0-3 (j<128) -> tb bf16; waves 4-7 -> out fp32 + bias.
#pragma unroll
  for (int mt = 0; mt < 4; mt++) {
#pragma unroll
    for (int nt = 0; nt < 2; nt++) {
      const int j = wn + nt * 16 + l15;
      const float bv = nt ? cv1 : cv0;
#pragma unroll
      for (int r = 0; r < 4; r++) {
        const int node = m_blk + mt * 16 + quad * 4 + r;
        if (node >= M) continue;
        const float v = acc[mt][nt][r];
        if (j < 128) {
          tb[(size_t)node * 128 + j] = f2b(v);
        } else {
          out[(size_t)node * 128 + (j - 128)] = v + bv;
        }
      }
    }
  }
}

extern "C" void kernel_launch(void* const* d_in, const int* in_sizes, int n_in,
                              void* d_out, int out_size, void* d_ws, size_t ws_size,
                              hipStream_t stream) {
  const float* x   = (const float*)d_in[0];
  const int*  eidx = (const int*)d_in[1];
  const float* W1l = (const float*)d_in[2];
  const float* b1l = (const float*)d_in[3];
  const float* W1r = (const float*)d_in[4];
  const float* W2l = (const float*)d_in[5];
  const float* b2l = (const float*)d_in[6];
  const float* W2r = (const float*)d_in[7];
  float* out = (float*)d_out;

  const int N = in_sizes[0] / 128;
  const int E = in_sizes[1] / 2;
  const int* src = eidx;
  const int* dst = eidx + E;

  int* cnt  = (int*)d_ws;          // [N]
  int* off  = cnt + N;             // [N+1]
  int* bsum = off + N + 1;         // [64]
  int* rank = bsum + 64;           // [E]
  int* csr  = rank + E;            // [E]
  size_t ioff = ((size_t)(N + N + 1 + 64 + 2 * E) * 4 + 15) & ~(size_t)15;
  unsigned short* A1  = (unsigned short*)((char*)d_ws + ioff);  // [N][256]
  unsigned short* tb  = A1 + (size_t)N * 256;                   // [N][128]
  unsigned short* Wc1 = tb + (size_t)N * 128;                   // [256][256]
  unsigned short* Wc2 = Wc1 + 65536;                            // [256][256]

  const int SB = (N + 1023) / 1024;  // 49

  prep_kernel<<<(N * 32 + 255) / 256, 256, 0, stream>>>(x, W1l, W1r, W2l, W2r,
                                                        Wc1, Wc2, A1, cnt, off, N, E);
  hist_kernel<<<(E / 4 + 255) / 256, 256, 0, stream>>>(dst, cnt, rank, E);
  scan_blocks_kernel<<<SB, 1024, 0, stream>>>(cnt, off, bsum, N);
  scan_add_kernel<<<SB, 1024, 0, stream>>>(off, bsum, N, SB);
  fill_kernel<<<(E / 4 + 255) / 256, 256, 0, stream>>>(src, dst, rank, off, csr, E);

  const int gblocks = (N + 3) / 4;  // 1 wave (64 lanes) per node
  gather1_kernel<<<gblocks, 256, 0, stream>>>(A1 + 128, csr, off, A1, N);

  gemm_fused<<<(N + 63) / 64, 512, 0, stream>>>(A1, Wc1, Wc2, b1l, b2l, tb, out, N);

  gather2_kernel<<<gblocks, 256, 0, stream>>>(tb, csr, off, out, N);
}

// Round 10
// 264.494 us; speedup vs baseline: 1.2661x; 1.0036x over previous
//
#include <hip/hip_runtime.h>

// GraphSAGE 2-layer. N=50000, E=800000, D_IN=128, D_H=256, D_OUT=128.
//
// R16: ONE change vs R15 — gemm_fused __launch_bounds__(512,4) -> (512,2).
// Evidence: VGPR_Count=64 while wr[2][8] alone needs 64 VGPRs; the (512,4)
// bound caps unified regs at 128/wave, so the compiler demoted the "resident"
// W fragments to in-loop L2 reloads (explains ~34K cycles/block vs ~4K
// expected, and why all register-resident-W variants measured identically to
// L2-streaming ones). (512,2) raises the cap to 256 regs/wave; achievable
// residency is unchanged (1x512-thr block/CU = 8 waves = 2/EU either way).
//
// Pipeline:
//   prep: Wc1/Wc2 bf16 pack | x->bf16 into A1 cols 128..255 | cnt=0 | off[N]=E
//   hist: rank[e] = cnt[dst[e]]++            (E int atomics, rank coalesced)
//   scan_blocks / scan_add: exclusive scan -> off
//   fill: csr[off[dst[e]] + rank[e]] = src[e]
//   gather1: A1 cols 0..127 = mean_{s in adj(n)} bf16(x[s])
//   gemm_fused: H=relu(A1@Wc1.T+b1) in LDS; tb=H@W2l.T (bf16);
//               out=H@W2r.T+b2l (fp32)
//   gather2: out[n] += mean_{s in adj(n)} tb[s]
//
// Layer-2 trick: mean(h[src])@W2l.T == mean((h@W2l.T)[src]).

typedef __attribute__((ext_vector_type(8))) short bf16x8;
typedef __attribute__((ext_vector_type(4))) float floatx4;

__device__ inline unsigned short f2b(float f) {
  unsigned int x = __float_as_uint(f);
  unsigned int r = (x + 0x7fffu + ((x >> 16) & 1u)) >> 16;
  return (unsigned short)r;
}
__device__ inline float blo(unsigned int u) { return __uint_as_float(u << 16); }
__device__ inline float bhi(unsigned int u) { return __uint_as_float(u & 0xffff0000u); }

// Fused prep: weight pack, x->bf16 convert, cnt zero, off[N]=E.
__global__ void prep_kernel(const float* __restrict__ x,
                            const float* __restrict__ W1l, const float* __restrict__ W1r,
                            const float* __restrict__ W2l, const float* __restrict__ W2r,
                            unsigned short* __restrict__ Wc1, unsigned short* __restrict__ Wc2,
                            unsigned short* __restrict__ A1,
                            int* __restrict__ cnt, int* __restrict__ off, int N, int E) {
  int i = blockIdx.x * blockDim.x + threadIdx.x;
  if (i < 65536) {
    int j = i >> 8, k = i & 255;
    float v1 = (k < 128) ? W1l[j * 128 + k] : W1r[j * 128 + (k - 128)];
    Wc1[i] = f2b(v1);
    float v2 = (j < 128) ? W2l[j * 256 + k] : W2r[(j - 128) * 256 + k];
    Wc2[i] = f2b(v2);
  }
  if (i < N) cnt[i] = 0;
  if (i == 0) off[N] = E;
  if (i < N * 32) {
    int n = i >> 5, c = (i & 31) * 4;
    float4 v = *(const float4*)(x + (size_t)n * 128 + c);
    uint2 p;
    p.x = (unsigned int)f2b(v.x) | ((unsigned int)f2b(v.y) << 16);
    p.y = (unsigned int)f2b(v.z) | ((unsigned int)f2b(v.w) << 16);
    *(uint2*)(A1 + (size_t)n * 256 + 128 + c) = p;
  }
}

// Histogram + per-edge rank capture (4 edges/thread, vectorized loads).
__global__ void hist_kernel(const int* __restrict__ dst, int* __restrict__ cnt,
                            int* __restrict__ rank, int E) {
  int i = blockIdx.x * blockDim.x + threadIdx.x;
  int e = i * 4;
  if (e + 3 < E) {
    int4 d = *(const int4*)(dst + e);
    int4 r;
    r.x = atomicAdd(&cnt[d.x], 1);
    r.y = atomicAdd(&cnt[d.y], 1);
    r.z = atomicAdd(&cnt[d.z], 1);
    r.w = atomicAdd(&cnt[d.w], 1);
    *(int4*)(rank + e) = r;
  } else {
    for (; e < E; e++) rank[e] = atomicAdd(&cnt[dst[e]], 1);
  }
}

// Per-1024-block exclusive scan; block total -> bsum[b].
__global__ __launch_bounds__(1024) void scan_blocks_kernel(const int* __restrict__ cnt,
                                                           int* __restrict__ off,
                                                           int* __restrict__ bsum, int N) {
  __shared__ int wsum[16];
  __shared__ int wincl[16];
  const int tid = threadIdx.x;
  const int lane = tid & 63;
  const int wv = tid >> 6;
  const int i = blockIdx.x * 1024 + tid;
  const int v = (i < N) ? cnt[i] : 0;
  int s = v;
#pragma unroll
  for (int o = 1; o < 64; o <<= 1) {
    int t = __shfl_up(s, o, 64);
    if (lane >= o) s += t;
  }
  if (lane == 63) wsum[wv] = s;
  __syncthreads();
  if (tid < 16) {
    int ws = wsum[tid];
#pragma unroll
    for (int o = 1; o < 16; o <<= 1) {
      int t = __shfl_up(ws, o, 16);
      if ((tid & 15) >= o) ws += t;
    }
    wincl[tid] = ws;
  }
  __syncthreads();
  const int wo = wv ? wincl[wv - 1] : 0;
  if (i < N) off[i] = wo + s - v;
  if (tid == 1023) bsum[blockIdx.x] = wo + s;
}

// Add block offsets (block-sum scan inlined: <=64 sums, wave 0).
__global__ __launch_bounds__(1024) void scan_add_kernel(int* __restrict__ off,
                                                        const int* __restrict__ bsum, int N, int SB) {
  __shared__ int bofs[64];
  const int tid = threadIdx.x;
  if (tid < 64) {
    int v = (tid < SB) ? bsum[tid] : 0;
    int s = v;
#pragma unroll
    for (int o = 1; o < 64; o <<= 1) {
      int t = __shfl_up(s, o, 64);
      if (tid >= o) s += t;
    }
    bofs[tid] = s - v;
  }
  __syncthreads();
  int i = blockIdx.x * 1024 + tid;
  if (i < N) off[i] = off[i] + bofs[blockIdx.x];
}

// Atomic-free fill: plain scattered stores, 4 edges/thread.
__global__ void fill_kernel(const int* __restrict__ src, const int* __restrict__ dst,
                            const int* __restrict__ rank, const int* __restrict__ off,
                            int* __restrict__ csr, int E) {
  int i = blockIdx.x * blockDim.x + threadIdx.x;
  int e = i * 4;
  if (e + 3 < E) {
    int4 d = *(const int4*)(dst + e);
    int4 r = *(const int4*)(rank + e);
    int4 s = *(const int4*)(src + e);
    csr[off[d.x] + r.x] = s.x;
    csr[off[d.y] + r.y] = s.y;
    csr[off[d.z] + r.z] = s.z;
    csr[off[d.w] + r.w] = s.w;
  } else {
    for (; e < E; e++) csr[off[dst[e]] + rank[e]] = src[e];
  }
}

// Gather-mean, one wave per node, 64 lanes per edge-row. Lane l owns columns
// 2l,2l+1 (one dword of the 256B row): no cross-lane reduction; coalesced
// 1-dword/lane loads. 8-edge unroll -> 8 row-loads outstanding; 2-edge
// mid-tail. Edge ids via lane-parallel csr read + __shfl broadcast.
__global__ void gather1_kernel(const unsigned short* __restrict__ feat,
                               const int* __restrict__ csr, const int* __restrict__ off,
                               unsigned short* __restrict__ ob, int N) {
  int wid = (blockIdx.x * blockDim.x + threadIdx.x) >> 6;
  if (wid >= N) return;
  const int lane = threadIdx.x & 63;
  const int s0 = off[wid], s1 = off[wid + 1];
  float a0 = 0.f, a1 = 0.f;
  for (int base = s0; base < s1; base += 64) {
    const int cnt = min(64, s1 - base);
    int my = (lane < cnt) ? csr[base + lane] : 0;
    int k = 0;
    for (; k + 8 <= cnt; k += 8) {
      int i0 = __shfl(my, k);
      int i1 = __shfl(my, k + 1);
      int i2 = __shfl(my, k + 2);
      int i3 = __shfl(my, k + 3);
      int i4 = __shfl(my, k + 4);
      int i5 = __shfl(my, k + 5);
      int i6 = __shfl(my, k + 6);
      int i7 = __shfl(my, k + 7);
      unsigned u0 = ((const unsigned*)(feat + (size_t)i0 * 256))[lane];
      unsigned u1 = ((const unsigned*)(feat + (size_t)i1 * 256))[lane];
      unsigned u2 = ((const unsigned*)(feat + (size_t)i2 * 256))[lane];
      unsigned u3 = ((const unsigned*)(feat + (size_t)i3 * 256))[lane];
      unsigned u4 = ((const unsigned*)(feat + (size_t)i4 * 256))[lane];
      unsigned u5 = ((const unsigned*)(feat + (size_t)i5 * 256))[lane];
      unsigned u6 = ((const unsigned*)(feat + (size_t)i6 * 256))[lane];
      unsigned u7 = ((const unsigned*)(feat + (size_t)i7 * 256))[lane];
      a0 += blo(u0); a1 += bhi(u0);
      a0 += blo(u1); a1 += bhi(u1);
      a0 += blo(u2); a1 += bhi(u2);
      a0 += blo(u3); a1 += bhi(u3);
      a0 += blo(u4); a1 += bhi(u4);
      a0 += blo(u5); a1 += bhi(u5);
      a0 += blo(u6); a1 += bhi(u6);
      a0 += blo(u7); a1 += bhi(u7);
    }
    for (; k + 2 <= cnt; k += 2) {
      int i0 = __shfl(my, k);
      int i1 = __shfl(my, k + 1);
      unsigned u0 = ((const unsigned*)(feat + (size_t)i0 * 256))[lane];
      unsigned u1 = ((const unsigned*)(feat + (size_t)i1 * 256))[lane];
      a0 += blo(u0); a1 += bhi(u0);
      a0 += blo(u1); a1 += bhi(u1);
    }
    if (k < cnt) {
      int i0 = __shfl(my, k);
      unsigned u0 = ((const unsigned*)(feat + (size_t)i0 * 256))[lane];
      a0 += blo(u0); a1 += bhi(u0);
    }
  }
  const float inv = 1.0f / fmaxf((float)(s1 - s0), 1.0f);
  unsigned p = (unsigned)f2b(a0 * inv) | ((unsigned)f2b(a1 * inv) << 16);
  ((unsigned*)(ob + (size_t)wid * 256))[lane] = p;
}

// Same structure; feat (tb) stride 128 ushorts; accumulate into fp32 out.
// out row prefetched BEFORE the loop (overlaps gather latency).
__global__ void gather2_kernel(const unsigned short* __restrict__ t,
                               const int* __restrict__ csr, const int* __restrict__ off,
                               float* __restrict__ out, int N) {
  int wid = (blockIdx.x * blockDim.x + threadIdx.x) >> 6;
  if (wid >= N) return;
  const int lane = threadIdx.x & 63;
  const int s0 = off[wid], s1 = off[wid + 1];
  float2* op = (float2*)(out + (size_t)wid * 128) + lane;
  float2 r = *op;  // prefetch RMW operand early
  float a0 = 0.f, a1 = 0.f;
  for (int base = s0; base < s1; base += 64) {
    const int cnt = min(64, s1 - base);
    int my = (lane < cnt) ? csr[base + lane] : 0;
    int k = 0;
    for (; k + 8 <= cnt; k += 8) {
      int i0 = __shfl(my, k);
      int i1 = __shfl(my, k + 1);
      int i2 = __shfl(my, k + 2);
      int i3 = __shfl(my, k + 3);
      int i4 = __shfl(my, k + 4);
      int i5 = __shfl(my, k + 5);
      int i6 = __shfl(my, k + 6);
      int i7 = __shfl(my, k + 7);
      unsigned u0 = ((const unsigned*)(t + (size_t)i0 * 128))[lane];
      unsigned u1 = ((const unsigned*)(t + (size_t)i1 * 128))[lane];
      unsigned u2 = ((const unsigned*)(t + (size_t)i2 * 128))[lane];
      unsigned u3 = ((const unsigned*)(t + (size_t)i3 * 128))[lane];
      unsigned u4 = ((const unsigned*)(t + (size_t)i4 * 128))[lane];
      unsigned u5 = ((const unsigned*)(t + (size_t)i5 * 128))[lane];
      unsigned u6 = ((const unsigned*)(t + (size_t)i6 * 128))[lane];
      unsigned u7 = ((const unsigned*)(t + (size_t)i7 * 128))[lane];
      a0 += blo(u0); a1 += bhi(u0);
      a0 += blo(u1); a1 += bhi(u1);
      a0 += blo(u2); a1 += bhi(u2);
      a0 += blo(u3); a1 += bhi(u3);
      a0 += blo(u4); a1 += bhi(u4);
      a0 += blo(u5); a1 += bhi(u5);
      a0 += blo(u6); a1 += bhi(u6);
      a0 += blo(u7); a1 += bhi(u7);
    }
    for (; k + 2 <= cnt; k += 2) {
      int i0 = __shfl(my, k);
      int i1 = __shfl(my, k + 1);
      unsigned u0 = ((const unsigned*)(t + (size_t)i0 * 128))[lane];
      unsigned u1 = ((const unsigned*)(t + (size_t)i1 * 128))[lane];
      a0 += blo(u0); a1 += bhi(u0);
      a0 += blo(u1); a1 += bhi(u1);
    }
    if (k < cnt) {
      int i0 = __shfl(my, k);
      unsigned u0 = ((const unsigned*)(t + (size_t)i0 * 128))[lane];
      a0 += blo(u0); a1 += bhi(u0);
    }
  }
  const float inv = 1.0f / fmaxf((float)(s1 - s0), 1.0f);
  r.x += a0 * inv;
  r.y += a1 * inv;
  *op = r;
}

// Fused 2-layer bf16 MFMA GEMM. 512 thr = 8 waves; wave w owns rows 0..63 x
// cols [w*32,w*32+32). Phase A: wr=W1 frags (wr[2][8]=64 VGPR, loaded once
// from L2 — ACTUALLY resident now that launch_bounds(512,2) allows 256
// regs/wave), A-tile staged to LDS (LDA=264, conflict-free b128);
// H=relu(acc+b1) -> Hs (LDS). Reload wr=W2 frags; phase B: acc=Hs@W2.T;
// waves 0-3: tb=bf16(acc); waves 4-7: out=acc+b2. 2 barriers; no global
// loads inside MFMA loops.
__global__ __launch_bounds__(512, 2)
void gemm_fused(const unsigned short* __restrict__ A, const unsigned short* __restrict__ Wc1,
                const unsigned short* __restrict__ Wc2,
                const float* __restrict__ b1, const float* __restrict__ b2,
                unsigned short* __restrict__ tb, float* __restrict__ out, int M) {
  constexpr int LDA = 264;
  __shared__ __align__(16) unsigned short As[64 * LDA];
  __shared__ __align__(16) unsigned short Hs[64 * LDA];
  const int t = threadIdx.x;
  const int lane = t & 63;
  const int wave = t >> 6;
  const int wn = wave * 32;
  const int l15 = lane & 15;
  const int quad = lane >> 4;
  const int m_blk = blockIdx.x * 64;

  // Resident W1 fragments: j = wn + nt*16 + l15, k = c*32 + quad*8.
  bf16x8 wr[2][8];
#pragma unroll
  for (int nt = 0; nt < 2; nt++) {
    const unsigned short* wp = Wc1 + (size_t)(wn + nt * 16 + l15) * 256 + quad * 8;
#pragma unroll
    for (int c = 0; c < 8; c++) wr[nt][c] = *(const bf16x8*)(wp + c * 32);
  }
  const float bv0 = b1[wn + l15];
  const float bv1 = b1[wn + 16 + l15];

  // Stage A tile (64 rows x 256 k = 32 KB).
#pragma unroll
  for (int i = 0; i < 4; i++) {
    int idx = t + 512 * i;
    int row = idx >> 5, cc = (idx & 31) * 8;
    int ar = m_blk + row;
    if (ar >= M) ar = M - 1;
    *(uint4*)(As + row * LDA + cc) = *(const uint4*)(A + (size_t)ar * 256 + cc);
  }
  __syncthreads();

  // ---- Phase A: acc = A @ Wc1.T ----
  floatx4 acc[4][2] = {};
#pragma unroll
  for (int c = 0; c < 8; c++) {
    bf16x8 af[4];
#pragma unroll
    for (int mt = 0; mt < 4; mt++)
      af[mt] = *(const bf16x8*)(As + (mt * 16 + l15) * LDA + c * 32 + quad * 8);
#pragma unroll
    for (int mt = 0; mt < 4; mt++) {
      acc[mt][0] = __builtin_amdgcn_mfma_f32_16x16x32_bf16(af[mt], wr[0][c], acc[mt][0], 0, 0, 0);
      acc[mt][1] = __builtin_amdgcn_mfma_f32_16x16x32_bf16(af[mt], wr[1][c], acc[mt][1], 0, 0, 0);
    }
  }

  // Epilogue A: H = relu(acc + b1) into Hs.
#pragma unroll
  for (int mt = 0; mt < 4; mt++) {
#pragma unroll
    for (int nt = 0; nt < 2; nt++) {
      const int jl = wn + nt * 16 + l15;
      const float bv = nt ? bv1 : bv0;
#pragma unroll
      for (int r = 0; r < 4; r++) {
        const int row = mt * 16 + quad * 4 + r;
        Hs[row * LDA + jl] = f2b(fmaxf(acc[mt][nt][r] + bv, 0.f));
      }
    }
  }

  // Reload wr with W2 fragments (independent of Hs; overlaps other waves'
  // epilogue work before the barrier).
#pragma unroll
  for (int nt = 0; nt < 2; nt++) {
    const unsigned short* wp = Wc2 + (size_t)(wn + nt * 16 + l15) * 256 + quad * 8;
#pragma unroll
    for (int c = 0; c < 8; c++) wr[nt][c] = *(const bf16x8*)(wp + c * 32);
  }
  const float cv0 = (wn >= 128) ? b2[wn - 128 + l15] : 0.f;
  const float cv1 = (wn >= 128) ? b2[wn - 112 + l15] : 0.f;
  __syncthreads();

  // ---- Phase B: acc = Hs @ Wc2.T ----
#pragma unroll
  for (int mt = 0; mt < 4; mt++) {
    acc[mt][0] = (floatx4){0.f, 0.f, 0.f, 0.f};
    acc[mt][1] = (floatx4){0.f, 0.f, 0.f, 0.f};
  }
#pragma unroll
  for (int c = 0; c < 8; c++) {
    bf16x8 af[4];
#pragma unroll
    for (int mt = 0; mt < 4; mt++)
      af[mt] = *(const bf16x8*)(Hs + (mt * 16 + l15) * LDA + c * 32 + quad * 8);
#pragma unroll
    for (int mt = 0; mt < 4; mt++) {
      acc[mt][0] = __builtin_amdgcn_mfma_f32_16x16x32_bf16(af[mt], wr[0][c], acc[mt][0], 0, 0, 0);
      acc[mt][1] = __builtin_amdgcn_mfma_f32_16x16x32_bf16(af[mt], wr[1][c], acc[mt][1], 0, 0, 0);
    }
  }

  // Epilogue B: waves 0-3 (j<128) -> tb bf16; waves 4-7 -> out fp32 + bias.
#pragma unroll
  for (int mt = 0; mt < 4; mt++) {
#pragma unroll
    for (int nt = 0; nt < 2; nt++) {
      const int j = wn + nt * 16 + l15;
      const float bv = nt ? cv1 : cv0;
#pragma unroll
      for (int r = 0; r < 4; r++) {
        const int node = m_blk + mt * 16 + quad * 4 + r;
        if (node >= M) continue;
        const float v = acc[mt][nt][r];
        if (j < 128) {
          tb[(size_t)node * 128 + j] = f2b(v);
        } else {
          out[(size_t)node * 128 + (j - 128)] = v + bv;
        }
      }
    }
  }
}

extern "C" void kernel_launch(void* const* d_in, const int* in_sizes, int n_in,
                              void* d_out, int out_size, void* d_ws, size_t ws_size,
                              hipStream_t stream) {
  const float* x   = (const float*)d_in[0];
  const int*  eidx = (const int*)d_in[1];
  const float* W1l = (const float*)d_in[2];
  const float* b1l = (const float*)d_in[3];
  const float* W1r = (const float*)d_in[4];
  const float* W2l = (const float*)d_in[5];
  const float* b2l = (const float*)d_in[6];
  const float* W2r = (const float*)d_in[7];
  float* out = (float*)d_out;

  const int N = in_sizes[0] / 128;
  const int E = in_sizes[1] / 2;
  const int* src = eidx;
  const int* dst = eidx + E;

  int* cnt  = (int*)d_ws;          // [N]
  int* off  = cnt + N;             // [N+1]
  int* bsum = off + N + 1;         // [64]
  int* rank = bsum + 64;           // [E]
  int* csr  = rank + E;            // [E]
  size_t ioff = ((size_t)(N + N + 1 + 64 + 2 * E) * 4 + 15) & ~(size_t)15;
  unsigned short* A1  = (unsigned short*)((char*)d_ws + ioff);  // [N][256]
  unsigned short* tb  = A1 + (size_t)N * 256;                   // [N][128]
  unsigned short* Wc1 = tb + (size_t)N * 128;                   // [256][256]
  unsigned short* Wc2 = Wc1 + 65536;                            // [256][256]

  const int SB = (N + 1023) / 1024;  // 49

  prep_kernel<<<(N * 32 + 255) / 256, 256, 0, stream>>>(x, W1l, W1r, W2l, W2r,
                                                        Wc1, Wc2, A1, cnt, off, N, E);
  hist_kernel<<<(E / 4 + 255) / 256, 256, 0, stream>>>(dst, cnt, rank, E);
  scan_blocks_kernel<<<SB, 1024, 0, stream>>>(cnt, off, bsum, N);
  scan_add_kernel<<<SB, 1024, 0, stream>>>(off, bsum, N, SB);
  fill_kernel<<<(E / 4 + 255) / 256, 256, 0, stream>>>(src, dst, rank, off, csr, E);

  const int gblocks = (N + 3) / 4;  // 1 wave (64 lanes) per node
  gather1_kernel<<<gblocks, 256, 0, stream>>>(A1 + 128, csr, off, A1, N);

  gemm_fused<<<(N + 63) / 64, 512, 0, stream>>>(A1, Wc1, Wc2, b1l, b2l, tb, out, N);

  gather2_kernel<<<gblocks, 256, 0, stream>>>(tb, csr, off, out, N);
}

// Round 11
// 262.702 us; speedup vs baseline: 1.2748x; 1.0068x over previous
//
#include <hip/hip_runtime.h>

// GraphSAGE 2-layer. N=50000, E=800000, D_IN=128, D_H=256, D_OUT=128.
//
// R17: BM=64 -> BM=128 in gemm_fused. Accounting from R15/R16: 1 block/CU
// resident (unified regs ~160/wave), per-block critical path ~35K cycles
// dominated by FIXED per-block W traffic (256KB L2) + staging + stores, all
// serially exposed. Doubling BM halves block count (782->391, 1.53 rounds/CU)
// and halves aggregate W traffic (200->100MB) while per-block cost grows
// sub-linearly. As/Hs aliased in ONE 67.6KB buffer (R12-style, measured
// cost-neutral); wr[2][8] W-frags resident (AGPR); acc[8][2]; 3 barriers.
// R16 lesson: W was already register-resident (AGPR) — launch_bounds knob
// was irrelevant; the lever is traffic amortization, not residency.
//
// Pipeline:
//   prep: Wc1/Wc2 bf16 pack | x->bf16 into A1 cols 128..255 | cnt=0 | off[N]=E
//   hist: rank[e] = cnt[dst[e]]++            (E int atomics, rank coalesced)
//   scan_blocks / scan_add: exclusive scan -> off
//   fill: csr[off[dst[e]] + rank[e]] = src[e]
//   gather1: A1 cols 0..127 = mean_{s in adj(n)} bf16(x[s])
//   gemm_fused: H=relu(A1@Wc1.T+b1) in LDS; tb=H@W2l.T (bf16);
//               out=H@W2r.T+b2l (fp32)
//   gather2: out[n] += mean_{s in adj(n)} tb[s]
//
// Layer-2 trick: mean(h[src])@W2l.T == mean((h@W2l.T)[src]).

typedef __attribute__((ext_vector_type(8))) short bf16x8;
typedef __attribute__((ext_vector_type(4))) float floatx4;

__device__ inline unsigned short f2b(float f) {
  unsigned int x = __float_as_uint(f);
  unsigned int r = (x + 0x7fffu + ((x >> 16) & 1u)) >> 16;
  return (unsigned short)r;
}
__device__ inline float blo(unsigned int u) { return __uint_as_float(u << 16); }
__device__ inline float bhi(unsigned int u) { return __uint_as_float(u & 0xffff0000u); }

// Fused prep: weight pack, x->bf16 convert, cnt zero, off[N]=E.
__global__ void prep_kernel(const float* __restrict__ x,
                            const float* __restrict__ W1l, const float* __restrict__ W1r,
                            const float* __restrict__ W2l, const float* __restrict__ W2r,
                            unsigned short* __restrict__ Wc1, unsigned short* __restrict__ Wc2,
                            unsigned short* __restrict__ A1,
                            int* __restrict__ cnt, int* __restrict__ off, int N, int E) {
  int i = blockIdx.x * blockDim.x + threadIdx.x;
  if (i < 65536) {
    int j = i >> 8, k = i & 255;
    float v1 = (k < 128) ? W1l[j * 128 + k] : W1r[j * 128 + (k - 128)];
    Wc1[i] = f2b(v1);
    float v2 = (j < 128) ? W2l[j * 256 + k] : W2r[(j - 128) * 256 + k];
    Wc2[i] = f2b(v2);
  }
  if (i < N) cnt[i] = 0;
  if (i == 0) off[N] = E;
  if (i < N * 32) {
    int n = i >> 5, c = (i & 31) * 4;
    float4 v = *(const float4*)(x + (size_t)n * 128 + c);
    uint2 p;
    p.x = (unsigned int)f2b(v.x) | ((unsigned int)f2b(v.y) << 16);
    p.y = (unsigned int)f2b(v.z) | ((unsigned int)f2b(v.w) << 16);
    *(uint2*)(A1 + (size_t)n * 256 + 128 + c) = p;
  }
}

// Histogram + per-edge rank capture (4 edges/thread, vectorized loads).
__global__ void hist_kernel(const int* __restrict__ dst, int* __restrict__ cnt,
                            int* __restrict__ rank, int E) {
  int i = blockIdx.x * blockDim.x + threadIdx.x;
  int e = i * 4;
  if (e + 3 < E) {
    int4 d = *(const int4*)(dst + e);
    int4 r;
    r.x = atomicAdd(&cnt[d.x], 1);
    r.y = atomicAdd(&cnt[d.y], 1);
    r.z = atomicAdd(&cnt[d.z], 1);
    r.w = atomicAdd(&cnt[d.w], 1);
    *(int4*)(rank + e) = r;
  } else {
    for (; e < E; e++) rank[e] = atomicAdd(&cnt[dst[e]], 1);
  }
}

// Per-1024-block exclusive scan; block total -> bsum[b].
__global__ __launch_bounds__(1024) void scan_blocks_kernel(const int* __restrict__ cnt,
                                                           int* __restrict__ off,
                                                           int* __restrict__ bsum, int N) {
  __shared__ int wsum[16];
  __shared__ int wincl[16];
  const int tid = threadIdx.x;
  const int lane = tid & 63;
  const int wv = tid >> 6;
  const int i = blockIdx.x * 1024 + tid;
  const int v = (i < N) ? cnt[i] : 0;
  int s = v;
#pragma unroll
  for (int o = 1; o < 64; o <<= 1) {
    int t = __shfl_up(s, o, 64);
    if (lane >= o) s += t;
  }
  if (lane == 63) wsum[wv] = s;
  __syncthreads();
  if (tid < 16) {
    int ws = wsum[tid];
#pragma unroll
    for (int o = 1; o < 16; o <<= 1) {
      int t = __shfl_up(ws, o, 16);
      if ((tid & 15) >= o) ws += t;
    }
    wincl[tid] = ws;
  }
  __syncthreads();
  const int wo = wv ? wincl[wv - 1] : 0;
  if (i < N) off[i] = wo + s - v;
  if (tid == 1023) bsum[blockIdx.x] = wo + s;
}

// Add block offsets (block-sum scan inlined: <=64 sums, wave 0).
__global__ __launch_bounds__(1024) void scan_add_kernel(int* __restrict__ off,
                                                        const int* __restrict__ bsum, int N, int SB) {
  __shared__ int bofs[64];
  const int tid = threadIdx.x;
  if (tid < 64) {
    int v = (tid < SB) ? bsum[tid] : 0;
    int s = v;
#pragma unroll
    for (int o = 1; o < 64; o <<= 1) {
      int t = __shfl_up(s, o, 64);
      if (tid >= o) s += t;
    }
    bofs[tid] = s - v;
  }
  __syncthreads();
  int i = blockIdx.x * 1024 + tid;
  if (i < N) off[i] = off[i] + bofs[blockIdx.x];
}

// Atomic-free fill: plain scattered stores, 4 edges/thread.
__global__ void fill_kernel(const int* __restrict__ src, const int* __restrict__ dst,
                            const int* __restrict__ rank, const int* __restrict__ off,
                            int* __restrict__ csr, int E) {
  int i = blockIdx.x * blockDim.x + threadIdx.x;
  int e = i * 4;
  if (e + 3 < E) {
    int4 d = *(const int4*)(dst + e);
    int4 r = *(const int4*)(rank + e);
    int4 s = *(const int4*)(src + e);
    csr[off[d.x] + r.x] = s.x;
    csr[off[d.y] + r.y] = s.y;
    csr[off[d.z] + r.z] = s.z;
    csr[off[d.w] + r.w] = s.w;
  } else {
    for (; e < E; e++) csr[off[dst[e]] + rank[e]] = src[e];
  }
}

// Gather-mean, one wave per node, 64 lanes per edge-row. Lane l owns columns
// 2l,2l+1 (one dword of the 256B row): no cross-lane reduction; coalesced
// 1-dword/lane loads. 8-edge unroll -> 8 row-loads outstanding; 2-edge
// mid-tail. Edge ids via lane-parallel csr read + __shfl broadcast.
__global__ void gather1_kernel(const unsigned short* __restrict__ feat,
                               const int* __restrict__ csr, const int* __restrict__ off,
                               unsigned short* __restrict__ ob, int N) {
  int wid = (blockIdx.x * blockDim.x + threadIdx.x) >> 6;
  if (wid >= N) return;
  const int lane = threadIdx.x & 63;
  const int s0 = off[wid], s1 = off[wid + 1];
  float a0 = 0.f, a1 = 0.f;
  for (int base = s0; base < s1; base += 64) {
    const int cnt = min(64, s1 - base);
    int my = (lane < cnt) ? csr[base + lane] : 0;
    int k = 0;
    for (; k + 8 <= cnt; k += 8) {
      int i0 = __shfl(my, k);
      int i1 = __shfl(my, k + 1);
      int i2 = __shfl(my, k + 2);
      int i3 = __shfl(my, k + 3);
      int i4 = __shfl(my, k + 4);
      int i5 = __shfl(my, k + 5);
      int i6 = __shfl(my, k + 6);
      int i7 = __shfl(my, k + 7);
      unsigned u0 = ((const unsigned*)(feat + (size_t)i0 * 256))[lane];
      unsigned u1 = ((const unsigned*)(feat + (size_t)i1 * 256))[lane];
      unsigned u2 = ((const unsigned*)(feat + (size_t)i2 * 256))[lane];
      unsigned u3 = ((const unsigned*)(feat + (size_t)i3 * 256))[lane];
      unsigned u4 = ((const unsigned*)(feat + (size_t)i4 * 256))[lane];
      unsigned u5 = ((const unsigned*)(feat + (size_t)i5 * 256))[lane];
      unsigned u6 = ((const unsigned*)(feat + (size_t)i6 * 256))[lane];
      unsigned u7 = ((const unsigned*)(feat + (size_t)i7 * 256))[lane];
      a0 += blo(u0); a1 += bhi(u0);
      a0 += blo(u1); a1 += bhi(u1);
      a0 += blo(u2); a1 += bhi(u2);
      a0 += blo(u3); a1 += bhi(u3);
      a0 += blo(u4); a1 += bhi(u4);
      a0 += blo(u5); a1 += bhi(u5);
      a0 += blo(u6); a1 += bhi(u6);
      a0 += blo(u7); a1 += bhi(u7);
    }
    for (; k + 2 <= cnt; k += 2) {
      int i0 = __shfl(my, k);
      int i1 = __shfl(my, k + 1);
      unsigned u0 = ((const unsigned*)(feat + (size_t)i0 * 256))[lane];
      unsigned u1 = ((const unsigned*)(feat + (size_t)i1 * 256))[lane];
      a0 += blo(u0); a1 += bhi(u0);
      a0 += blo(u1); a1 += bhi(u1);
    }
    if (k < cnt) {
      int i0 = __shfl(my, k);
      unsigned u0 = ((const unsigned*)(feat + (size_t)i0 * 256))[lane];
      a0 += blo(u0); a1 += bhi(u0);
    }
  }
  const float inv = 1.0f / fmaxf((float)(s1 - s0), 1.0f);
  unsigned p = (unsigned)f2b(a0 * inv) | ((unsigned)f2b(a1 * inv) << 16);
  ((unsigned*)(ob + (size_t)wid * 256))[lane] = p;
}

// Same structure; feat (tb) stride 128 ushorts; accumulate into fp32 out.
// out row prefetched BEFORE the loop (overlaps gather latency).
__global__ void gather2_kernel(const unsigned short* __restrict__ t,
                               const int* __restrict__ csr, const int* __restrict__ off,
                               float* __restrict__ out, int N) {
  int wid = (blockIdx.x * blockDim.x + threadIdx.x) >> 6;
  if (wid >= N) return;
  const int lane = threadIdx.x & 63;
  const int s0 = off[wid], s1 = off[wid + 1];
  float2* op = (float2*)(out + (size_t)wid * 128) + lane;
  float2 r = *op;  // prefetch RMW operand early
  float a0 = 0.f, a1 = 0.f;
  for (int base = s0; base < s1; base += 64) {
    const int cnt = min(64, s1 - base);
    int my = (lane < cnt) ? csr[base + lane] : 0;
    int k = 0;
    for (; k + 8 <= cnt; k += 8) {
      int i0 = __shfl(my, k);
      int i1 = __shfl(my, k + 1);
      int i2 = __shfl(my, k + 2);
      int i3 = __shfl(my, k + 3);
      int i4 = __shfl(my, k + 4);
      int i5 = __shfl(my, k + 5);
      int i6 = __shfl(my, k + 6);
      int i7 = __shfl(my, k + 7);
      unsigned u0 = ((const unsigned*)(t + (size_t)i0 * 128))[lane];
      unsigned u1 = ((const unsigned*)(t + (size_t)i1 * 128))[lane];
      unsigned u2 = ((const unsigned*)(t + (size_t)i2 * 128))[lane];
      unsigned u3 = ((const unsigned*)(t + (size_t)i3 * 128))[lane];
      unsigned u4 = ((const unsigned*)(t + (size_t)i4 * 128))[lane];
      unsigned u5 = ((const unsigned*)(t + (size_t)i5 * 128))[lane];
      unsigned u6 = ((const unsigned*)(t + (size_t)i6 * 128))[lane];
      unsigned u7 = ((const unsigned*)(t + (size_t)i7 * 128))[lane];
      a0 += blo(u0); a1 += bhi(u0);
      a0 += blo(u1); a1 += bhi(u1);
      a0 += blo(u2); a1 += bhi(u2);
      a0 += blo(u3); a1 += bhi(u3);
      a0 += blo(u4); a1 += bhi(u4);
      a0 += blo(u5); a1 += bhi(u5);
      a0 += blo(u6); a1 += bhi(u6);
      a0 += blo(u7); a1 += bhi(u7);
    }
    for (; k + 2 <= cnt; k += 2) {
      int i0 = __shfl(my, k);
      int i1 = __shfl(my, k + 1);
      unsigned u0 = ((const unsigned*)(t + (size_t)i0 * 128))[lane];
      unsigned u1 = ((const unsigned*)(t + (size_t)i1 * 128))[lane];
      a0 += blo(u0); a1 += bhi(u0);
      a0 += blo(u1); a1 += bhi(u1);
    }
    if (k < cnt) {
      int i0 = __shfl(my, k);
      unsigned u0 = ((const unsigned*)(t + (size_t)i0 * 128))[lane];
      a0 += blo(u0); a1 += bhi(u0);
    }
  }
  const float inv = 1.0f / fmaxf((float)(s1 - s0), 1.0f);
  r.x += a0 * inv;
  r.y += a1 * inv;
  *op = r;
}

// Fused 2-layer bf16 MFMA GEMM, BM=128. 512 thr = 8 waves; wave w owns
// m-rows 0..127 x j-cols [w*32,w*32+32). W frags wr[2][8] resident (AGPR);
// acc[8][2]. A/H share ONE aliased LDS buffer AH (128x264 = 67.6KB):
// stage A -> barrier -> phase A (reads all of AH) -> barrier -> write H into
// AH -> barrier -> phase B. No global loads inside MFMA loops.
__global__ __launch_bounds__(512, 2)
void gemm_fused(const unsigned short* __restrict__ A, const unsigned short* __restrict__ Wc1,
                const unsigned short* __restrict__ Wc2,
                const float* __restrict__ b1, const float* __restrict__ b2,
                unsigned short* __restrict__ tb, float* __restrict__ out, int M) {
  constexpr int LDA = 264;
  __shared__ __align__(16) unsigned short AH[128 * LDA];  // As, then Hs (aliased)
  const int t = threadIdx.x;
  const int lane = t & 63;
  const int wave = t >> 6;
  const int wn = wave * 32;
  const int l15 = lane & 15;
  const int quad = lane >> 4;
  const int m_blk = blockIdx.x * 128;

  // Resident W1 fragments: j = wn + nt*16 + l15, k = c*32 + quad*8.
  bf16x8 wr[2][8];
#pragma unroll
  for (int nt = 0; nt < 2; nt++) {
    const unsigned short* wp = Wc1 + (size_t)(wn + nt * 16 + l15) * 256 + quad * 8;
#pragma unroll
    for (int c = 0; c < 8; c++) wr[nt][c] = *(const bf16x8*)(wp + c * 32);
  }
  const float bv0 = b1[wn + l15];
  const float bv1 = b1[wn + 16 + l15];

  // Stage A tile (128 rows x 256 k = 64 KB).
#pragma unroll
  for (int i = 0; i < 8; i++) {
    int idx = t + 512 * i;
    int row = idx >> 5, cc = (idx & 31) * 8;
    int ar = m_blk + row;
    if (ar >= M) ar = M - 1;
    *(uint4*)(AH + row * LDA + cc) = *(const uint4*)(A + (size_t)ar * 256 + cc);
  }
  __syncthreads();

  // ---- Phase A: acc = A @ Wc1.T ----
  floatx4 acc[8][2] = {};
#pragma unroll
  for (int c = 0; c < 8; c++) {
    bf16x8 af[8];
#pragma unroll
    for (int mt = 0; mt < 8; mt++)
      af[mt] = *(const bf16x8*)(AH + (mt * 16 + l15) * LDA + c * 32 + quad * 8);
#pragma unroll
    for (int mt = 0; mt < 8; mt++) {
      acc[mt][0] = __builtin_amdgcn_mfma_f32_16x16x32_bf16(af[mt], wr[0][c], acc[mt][0], 0, 0, 0);
      acc[mt][1] = __builtin_amdgcn_mfma_f32_16x16x32_bf16(af[mt], wr[1][c], acc[mt][1], 0, 0, 0);
    }
  }

  // Reload wr with W2 fragments (independent of AH; overlaps barrier wait).
#pragma unroll
  for (int nt = 0; nt < 2; nt++) {
    const unsigned short* wp = Wc2 + (size_t)(wn + nt * 16 + l15) * 256 + quad * 8;
#pragma unroll
    for (int c = 0; c < 8; c++) wr[nt][c] = *(const bf16x8*)(wp + c * 32);
  }
  const float cv0 = (wn >= 128) ? b2[wn - 128 + l15] : 0.f;
  const float cv1 = (wn >= 128) ? b2[wn - 112 + l15] : 0.f;
  __syncthreads();  // all As reads done -> safe to overwrite with H

  // Epilogue A: H = relu(acc + b1) into AH (aliased).
#pragma unroll
  for (int mt = 0; mt < 8; mt++) {
#pragma unroll
    for (int nt = 0; nt < 2; nt++) {
      const int jl = wn + nt * 16 + l15;
      const float bv = nt ? bv1 : bv0;
#pragma unroll
      for (int r = 0; r < 4; r++) {
        const int row = mt * 16 + quad * 4 + r;
        AH[row * LDA + jl] = f2b(fmaxf(acc[mt][nt][r] + bv, 0.f));
      }
    }
  }
  __syncthreads();  // H complete

  // ---- Phase B: acc = H @ Wc2.T ----
#pragma unroll
  for (int mt = 0; mt < 8; mt++) {
    acc[mt][0] = (floatx4){0.f, 0.f, 0.f, 0.f};
    acc[mt][1] = (floatx4){0.f, 0.f, 0.f, 0.f};
  }
#pragma unroll
  for (int c = 0; c < 8; c++) {
    bf16x8 af[8];
#pragma unroll
    for (int mt = 0; mt < 8; mt++)
      af[mt] = *(const bf16x8*)(AH + (mt * 16 + l15) * LDA + c * 32 + quad * 8);
#pragma unroll
    for (int mt = 0; mt < 8; mt++) {
      acc[mt][0] = __builtin_amdgcn_mfma_f32_16x16x32_bf16(af[mt], wr[0][c], acc[mt][0], 0, 0, 0);
      acc[mt][1] = __builtin_amdgcn_mfma_f32_16x16x32_bf16(af[mt], wr[1][c], acc[mt][1], 0, 0, 0);
    }
  }

  // Epilogue B: waves 0-3 (j<128) -> tb bf16; waves 4-7 -> out fp32 + bias.
#pragma unroll
  for (int mt = 0; mt < 8; mt++) {
#pragma unroll
    for (int nt = 0; nt < 2; nt++) {
      const int j = wn + nt * 16 + l15;
      const float bv = nt ? cv1 : cv0;
#pragma unroll
      for (int r = 0; r < 4; r++) {
        const int node = m_blk + mt * 16 + quad * 4 + r;
        if (node >= M) continue;
        const float v = acc[mt][nt][r];
        if (j < 128) {
          tb[(size_t)node * 128 + j] = f2b(v);
        } else {
          out[(size_t)node * 128 + (j - 128)] = v + bv;
        }
      }
    }
  }
}

extern "C" void kernel_launch(void* const* d_in, const int* in_sizes, int n_in,
                              void* d_out, int out_size, void* d_ws, size_t ws_size,
                              hipStream_t stream) {
  const float* x   = (const float*)d_in[0];
  const int*  eidx = (const int*)d_in[1];
  const float* W1l = (const float*)d_in[2];
  const float* b1l = (const float*)d_in[3];
  const float* W1r = (const float*)d_in[4];
  const float* W2l = (const float*)d_in[5];
  const float* b2l = (const float*)d_in[6];
  const float* W2r = (const float*)d_in[7];
  float* out = (float*)d_out;

  const int N = in_sizes[0] / 128;
  const int E = in_sizes[1] / 2;
  const int* src = eidx;
  const int* dst = eidx + E;

  int* cnt  = (int*)d_ws;          // [N]
  int* off  = cnt + N;             // [N+1]
  int* bsum = off + N + 1;         // [64]
  int* rank = bsum + 64;           // [E]
  int* csr  = rank + E;            // [E]
  size_t ioff = ((size_t)(N + N + 1 + 64 + 2 * E) * 4 + 15) & ~(size_t)15;
  unsigned short* A1  = (unsigned short*)((char*)d_ws + ioff);  // [N][256]
  unsigned short* tb  = A1 + (size_t)N * 256;                   // [N][128]
  unsigned short* Wc1 = tb + (size_t)N * 128;                   // [256][256]
  unsigned short* Wc2 = Wc1 + 65536;                            // [256][256]

  const int SB = (N + 1023) / 1024;  // 49

  prep_kernel<<<(N * 32 + 255) / 256, 256, 0, stream>>>(x, W1l, W1r, W2l, W2r,
                                                        Wc1, Wc2, A1, cnt, off, N, E);
  hist_kernel<<<(E / 4 + 255) / 256, 256, 0, stream>>>(dst, cnt, rank, E);
  scan_blocks_kernel<<<SB, 1024, 0, stream>>>(cnt, off, bsum, N);
  scan_add_kernel<<<SB, 1024, 0, stream>>>(off, bsum, N, SB);
  fill_kernel<<<(E / 4 + 255) / 256, 256, 0, stream>>>(src, dst, rank, off, csr, E);

  const int gblocks = (N + 3) / 4;  // 1 wave (64 lanes) per node
  gather1_kernel<<<gblocks, 256, 0, stream>>>(A1 + 128, csr, off, A1, N);

  gemm_fused<<<(N + 127) / 128, 512, 0, stream>>>(A1, Wc1, Wc2, b1l, b2l, tb, out, N);

  gather2_kernel<<<gblocks, 256, 0, stream>>>(tb, csr, off, out, N);
}

// Round 13
// 260.475 us; speedup vs baseline: 1.2857x; 1.0085x over previous
//
#include <hip/hip_runtime.h>

// GraphSAGE 2-layer. N=50000, E=800000, D_IN=128, D_H=256, D_OUT=128.
//
// R19 = R18 with the workspace-alignment bug fixed. R18's rank/csr (u16)
// started at byte offset ≡4 mod 8, so hist's ushort4 stores / fill's ushort4
// loads were 8B-misaligned -> GPU fault -> container death. rank is now
// rounded up to 16B; csr = rank + E stays 16-aligned (2E = 1.6MB % 16 == 0).
//
// R18 content: (a) gathers do two-row loads — lanes 0-31 own edge e0, lanes
// 32-63 own e1, each lane reads uint2 (4 cols): same bytes/lines per edge,
// HALF the load+shfl+addr instructions; shfl_xor(.,32) fold x4 at the end;
// packed uint2/float4 outputs. (b) rank & csr u16 (ids<65536): halves
// coalesced CSR-path traffic. gemm frozen at R17 (BM=128 fused; ~527 cy/row
// stall floor confirmed across 6 structures).
//
// Pipeline:
//   prep | hist | scan_blocks/scan_add | fill  (CSR build, rank/csr u16)
//   gather1: A1 cols 0..127 = mean_{s in adj(n)} bf16(x[s])
//   gemm_fused: H=relu(A1@Wc1.T+b1) in LDS; tb=H@W2l.T (bf16);
//               out=H@W2r.T+b2l (fp32)
//   gather2: out[n] += mean_{s in adj(n)} tb[s]
//
// Layer-2 trick: mean(h[src])@W2l.T == mean((h@W2l.T)[src]).

typedef __attribute__((ext_vector_type(8))) short bf16x8;
typedef __attribute__((ext_vector_type(4))) float floatx4;

__device__ inline unsigned short f2b(float f) {
  unsigned int x = __float_as_uint(f);
  unsigned int r = (x + 0x7fffu + ((x >> 16) & 1u)) >> 16;
  return (unsigned short)r;
}
__device__ inline float blo(unsigned int u) { return __uint_as_float(u << 16); }
__device__ inline float bhi(unsigned int u) { return __uint_as_float(u & 0xffff0000u); }

// Fused prep: weight pack, x->bf16 convert, cnt zero, off[N]=E.
__global__ void prep_kernel(const float* __restrict__ x,
                            const float* __restrict__ W1l, const float* __restrict__ W1r,
                            const float* __restrict__ W2l, const float* __restrict__ W2r,
                            unsigned short* __restrict__ Wc1, unsigned short* __restrict__ Wc2,
                            unsigned short* __restrict__ A1,
                            int* __restrict__ cnt, int* __restrict__ off, int N, int E) {
  int i = blockIdx.x * blockDim.x + threadIdx.x;
  if (i < 65536) {
    int j = i >> 8, k = i & 255;
    float v1 = (k < 128) ? W1l[j * 128 + k] : W1r[j * 128 + (k - 128)];
    Wc1[i] = f2b(v1);
    float v2 = (j < 128) ? W2l[j * 256 + k] : W2r[(j - 128) * 256 + k];
    Wc2[i] = f2b(v2);
  }
  if (i < N) cnt[i] = 0;
  if (i == 0) off[N] = E;
  if (i < N * 32) {
    int n = i >> 5, c = (i & 31) * 4;
    float4 v = *(const float4*)(x + (size_t)n * 128 + c);
    uint2 p;
    p.x = (unsigned int)f2b(v.x) | ((unsigned int)f2b(v.y) << 16);
    p.y = (unsigned int)f2b(v.z) | ((unsigned int)f2b(v.w) << 16);
    *(uint2*)(A1 + (size_t)n * 256 + 128 + c) = p;
  }
}

// Histogram + per-edge rank capture (4 edges/thread; rank packed u16).
__global__ void hist_kernel(const int* __restrict__ dst, int* __restrict__ cnt,
                            unsigned short* __restrict__ rank, int E) {
  int i = blockIdx.x * blockDim.x + threadIdx.x;
  int e = i * 4;
  if (e + 3 < E) {
    int4 d = *(const int4*)(dst + e);
    ushort4 r;
    r.x = (unsigned short)atomicAdd(&cnt[d.x], 1);
    r.y = (unsigned short)atomicAdd(&cnt[d.y], 1);
    r.z = (unsigned short)atomicAdd(&cnt[d.z], 1);
    r.w = (unsigned short)atomicAdd(&cnt[d.w], 1);
    *(ushort4*)(rank + e) = r;
  } else {
    for (; e < E; e++) rank[e] = (unsigned short)atomicAdd(&cnt[dst[e]], 1);
  }
}

// Per-1024-block exclusive scan; block total -> bsum[b].
__global__ __launch_bounds__(1024) void scan_blocks_kernel(const int* __restrict__ cnt,
                                                           int* __restrict__ off,
                                                           int* __restrict__ bsum, int N) {
  __shared__ int wsum[16];
  __shared__ int wincl[16];
  const int tid = threadIdx.x;
  const int lane = tid & 63;
  const int wv = tid >> 6;
  const int i = blockIdx.x * 1024 + tid;
  const int v = (i < N) ? cnt[i] : 0;
  int s = v;
#pragma unroll
  for (int o = 1; o < 64; o <<= 1) {
    int t = __shfl_up(s, o, 64);
    if (lane >= o) s += t;
  }
  if (lane == 63) wsum[wv] = s;
  __syncthreads();
  if (tid < 16) {
    int ws = wsum[tid];
#pragma unroll
    for (int o = 1; o < 16; o <<= 1) {
      int t = __shfl_up(ws, o, 16);
      if ((tid & 15) >= o) ws += t;
    }
    wincl[tid] = ws;
  }
  __syncthreads();
  const int wo = wv ? wincl[wv - 1] : 0;
  if (i < N) off[i] = wo + s - v;
  if (tid == 1023) bsum[blockIdx.x] = wo + s;
}

// Add block offsets (block-sum scan inlined: <=64 sums, wave 0).
__global__ __launch_bounds__(1024) void scan_add_kernel(int* __restrict__ off,
                                                        const int* __restrict__ bsum, int N, int SB) {
  __shared__ int bofs[64];
  const int tid = threadIdx.x;
  if (tid < 64) {
    int v = (tid < SB) ? bsum[tid] : 0;
    int s = v;
#pragma unroll
    for (int o = 1; o < 64; o <<= 1) {
      int t = __shfl_up(s, o, 64);
      if (tid >= o) s += t;
    }
    bofs[tid] = s - v;
  }
  __syncthreads();
  int i = blockIdx.x * 1024 + tid;
  if (i < N) off[i] = off[i] + bofs[blockIdx.x];
}

// Atomic-free fill: plain scattered u16 stores, 4 edges/thread.
__global__ void fill_kernel(const int* __restrict__ src, const int* __restrict__ dst,
                            const unsigned short* __restrict__ rank, const int* __restrict__ off,
                            unsigned short* __restrict__ csr, int E) {
  int i = blockIdx.x * blockDim.x + threadIdx.x;
  int e = i * 4;
  if (e + 3 < E) {
    int4 d = *(const int4*)(dst + e);
    ushort4 r = *(const ushort4*)(rank + e);
    int4 s = *(const int4*)(src + e);
    csr[off[d.x] + r.x] = (unsigned short)s.x;
    csr[off[d.y] + r.y] = (unsigned short)s.y;
    csr[off[d.z] + r.z] = (unsigned short)s.z;
    csr[off[d.w] + r.w] = (unsigned short)s.w;
  } else {
    for (; e < E; e++) csr[off[dst[e]] + rank[e]] = (unsigned short)src[e];
  }
}

// Gather-mean, one wave per node, TWO rows per load round: lanes 0-31 own
// edge e0, lanes 32-63 own e1; each lane reads uint2 (cols 4c..4c+3, c=lane&31).
// 8 uint2 loads cover 16 edges (half the load/shfl/addr instructions of the
// one-row scheme); 4x shfl_xor(.,32) fold at the end; packed uint2 store.
__global__ void gather1_kernel(const unsigned short* __restrict__ feat,
                               const unsigned short* __restrict__ csr, const int* __restrict__ off,
                               unsigned short* __restrict__ ob, int N) {
  int wid = (blockIdx.x * blockDim.x + threadIdx.x) >> 6;
  if (wid >= N) return;
  const int lane = threadIdx.x & 63;
  const int half = lane >> 5;
  const int c = lane & 31;
  const int s0 = off[wid], s1 = off[wid + 1];
  float a0 = 0.f, a1 = 0.f, a2 = 0.f, a3 = 0.f;
  for (int base = s0; base < s1; base += 64) {
    const int cnt = min(64, s1 - base);
    int my = (lane < cnt) ? (int)csr[base + lane] : 0;
    int k = 0;
    for (; k + 16 <= cnt; k += 16) {
      int r[8];
#pragma unroll
      for (int p = 0; p < 8; p++) r[p] = __shfl(my, k + 2 * p + half);
      uint2 u[8];
#pragma unroll
      for (int p = 0; p < 8; p++)
        u[p] = ((const uint2*)(feat + (size_t)r[p] * 256))[c];
#pragma unroll
      for (int p = 0; p < 8; p++) {
        a0 += blo(u[p].x); a1 += bhi(u[p].x);
        a2 += blo(u[p].y); a3 += bhi(u[p].y);
      }
    }
    for (; k + 2 <= cnt; k += 2) {
      int r0 = __shfl(my, k + half);
      uint2 u = ((const uint2*)(feat + (size_t)r0 * 256))[c];
      a0 += blo(u.x); a1 += bhi(u.x);
      a2 += blo(u.y); a3 += bhi(u.y);
    }
    if (k < cnt) {
      int r0 = __shfl(my, k);  // all lanes execute the shfl; only half 0 loads
      if (half == 0) {
        uint2 u = ((const uint2*)(feat + (size_t)r0 * 256))[c];
        a0 += blo(u.x); a1 += bhi(u.x);
        a2 += blo(u.y); a3 += bhi(u.y);
      }
    }
  }
  a0 += __shfl_xor(a0, 32);
  a1 += __shfl_xor(a1, 32);
  a2 += __shfl_xor(a2, 32);
  a3 += __shfl_xor(a3, 32);
  if (half == 0) {
    const float inv = 1.0f / fmaxf((float)(s1 - s0), 1.0f);
    uint2 p;
    p.x = (unsigned)f2b(a0 * inv) | ((unsigned)f2b(a1 * inv) << 16);
    p.y = (unsigned)f2b(a2 * inv) | ((unsigned)f2b(a3 * inv) << 16);
    ((uint2*)(ob + (size_t)wid * 256))[c] = p;
  }
}

// Same structure; feat (tb) stride 128 ushorts; accumulate into fp32 out.
// out row (float4 per lane, lanes 0-31) prefetched BEFORE the loop.
__global__ void gather2_kernel(const unsigned short* __restrict__ t,
                               const unsigned short* __restrict__ csr, const int* __restrict__ off,
                               float* __restrict__ out, int N) {
  int wid = (blockIdx.x * blockDim.x + threadIdx.x) >> 6;
  if (wid >= N) return;
  const int lane = threadIdx.x & 63;
  const int half = lane >> 5;
  const int c = lane & 31;
  const int s0 = off[wid], s1 = off[wid + 1];
  float4* op = (float4*)(out + (size_t)wid * 128) + c;
  float4 rr;
  if (half == 0) rr = *op;  // prefetch RMW operand early
  float a0 = 0.f, a1 = 0.f, a2 = 0.f, a3 = 0.f;
  for (int base = s0; base < s1; base += 64) {
    const int cnt = min(64, s1 - base);
    int my = (lane < cnt) ? (int)csr[base + lane] : 0;
    int k = 0;
    for (; k + 16 <= cnt; k += 16) {
      int r[8];
#pragma unroll
      for (int p = 0; p < 8; p++) r[p] = __shfl(my, k + 2 * p + half);
      uint2 u[8];
#pragma unroll
      for (int p = 0; p < 8; p++)
        u[p] = ((const uint2*)(t + (size_t)r[p] * 128))[c];
#pragma unroll
      for (int p = 0; p < 8; p++) {
        a0 += blo(u[p].x); a1 += bhi(u[p].x);
        a2 += blo(u[p].y); a3 += bhi(u[p].y);
      }
    }
    for (; k + 2 <= cnt; k += 2) {
      int r0 = __shfl(my, k + half);
      uint2 u = ((const uint2*)(t + (size_t)r0 * 128))[c];
      a0 += blo(u.x); a1 += bhi(u.x);
      a2 += blo(u.y); a3 += bhi(u.y);
    }
    if (k < cnt) {
      int r0 = __shfl(my, k);
      if (half == 0) {
        uint2 u = ((const uint2*)(t + (size_t)r0 * 128))[c];
        a0 += blo(u.x); a1 += bhi(u.x);
        a2 += blo(u.y); a3 += bhi(u.y);
      }
    }
  }
  a0 += __shfl_xor(a0, 32);
  a1 += __shfl_xor(a1, 32);
  a2 += __shfl_xor(a2, 32);
  a3 += __shfl_xor(a3, 32);
  if (half == 0) {
    const float inv = 1.0f / fmaxf((float)(s1 - s0), 1.0f);
    rr.x += a0 * inv;
    rr.y += a1 * inv;
    rr.z += a2 * inv;
    rr.w += a3 * inv;
    *op = rr;
  }
}

// Fused 2-layer bf16 MFMA GEMM, BM=128 (R17, frozen). 512 thr = 8 waves;
// wave w owns m-rows 0..127 x j-cols [w*32,w*32+32). W frags wr[2][8]
// resident (AGPR); acc[8][2]. A/H share ONE aliased LDS buffer AH
// (128x264 = 67.6KB): stage A -> barrier -> phase A -> barrier -> H in place
// -> barrier -> phase B. No global loads inside MFMA loops.
__global__ __launch_bounds__(512, 2)
void gemm_fused(const unsigned short* __restrict__ A, const unsigned short* __restrict__ Wc1,
                const unsigned short* __restrict__ Wc2,
                const float* __restrict__ b1, const float* __restrict__ b2,
                unsigned short* __restrict__ tb, float* __restrict__ out, int M) {
  constexpr int LDA = 264;
  __shared__ __align__(16) unsigned short AH[128 * LDA];  // As, then Hs (aliased)
  const int t = threadIdx.x;
  const int lane = t & 63;
  const int wave = t >> 6;
  const int wn = wave * 32;
  const int l15 = lane & 15;
  const int quad = lane >> 4;
  const int m_blk = blockIdx.x * 128;

  // Resident W1 fragments: j = wn + nt*16 + l15, k = c*32 + quad*8.
  bf16x8 wr[2][8];
#pragma unroll
  for (int nt = 0; nt < 2; nt++) {
    const unsigned short* wp = Wc1 + (size_t)(wn + nt * 16 + l15) * 256 + quad * 8;
#pragma unroll
    for (int c = 0; c < 8; c++) wr[nt][c] = *(const bf16x8*)(wp + c * 32);
  }
  const float bv0 = b1[wn + l15];
  const float bv1 = b1[wn + 16 + l15];

  // Stage A tile (128 rows x 256 k = 64 KB).
#pragma unroll
  for (int i = 0; i < 8; i++) {
    int idx = t + 512 * i;
    int row = idx >> 5, cc = (idx & 31) * 8;
    int ar = m_blk + row;
    if (ar >= M) ar = M - 1;
    *(uint4*)(AH + row * LDA + cc) = *(const uint4*)(A + (size_t)ar * 256 + cc);
  }
  __syncthreads();

  // ---- Phase A: acc = A @ Wc1.T ----
  floatx4 acc[8][2] = {};
#pragma unroll
  for (int c = 0; c < 8; c++) {
    bf16x8 af[8];
#pragma unroll
    for (int mt = 0; mt < 8; mt++)
      af[mt] = *(const bf16x8*)(AH + (mt * 16 + l15) * LDA + c * 32 + quad * 8);
#pragma unroll
    for (int mt = 0; mt < 8; mt++) {
      acc[mt][0] = __builtin_amdgcn_mfma_f32_16x16x32_bf16(af[mt], wr[0][c], acc[mt][0], 0, 0, 0);
      acc[mt][1] = __builtin_amdgcn_mfma_f32_16x16x32_bf16(af[mt], wr[1][c], acc[mt][1], 0, 0, 0);
    }
  }

  // Reload wr with W2 fragments (independent of AH; overlaps barrier wait).
#pragma unroll
  for (int nt = 0; nt < 2; nt++) {
    const unsigned short* wp = Wc2 + (size_t)(wn + nt * 16 + l15) * 256 + quad * 8;
#pragma unroll
    for (int c = 0; c < 8; c++) wr[nt][c] = *(const bf16x8*)(wp + c * 32);
  }
  const float cv0 = (wn >= 128) ? b2[wn - 128 + l15] : 0.f;
  const float cv1 = (wn >= 128) ? b2[wn - 112 + l15] : 0.f;
  __syncthreads();  // all As reads done -> safe to overwrite with H

  // Epilogue A: H = relu(acc + b1) into AH (aliased).
#pragma unroll
  for (int mt = 0; mt < 8; mt++) {
#pragma unroll
    for (int nt = 0; nt < 2; nt++) {
      const int jl = wn + nt * 16 + l15;
      const float bv = nt ? bv1 : bv0;
#pragma unroll
      for (int r = 0; r < 4; r++) {
        const int row = mt * 16 + quad * 4 + r;
        AH[row * LDA + jl] = f2b(fmaxf(acc[mt][nt][r] + bv, 0.f));
      }
    }
  }
  __syncthreads();  // H complete

  // ---- Phase B: acc = H @ Wc2.T ----
#pragma unroll
  for (int mt = 0; mt < 8; mt++) {
    acc[mt][0] = (floatx4){0.f, 0.f, 0.f, 0.f};
    acc[mt][1] = (floatx4){0.f, 0.f, 0.f, 0.f};
  }
#pragma unroll
  for (int c = 0; c < 8; c++) {
    bf16x8 af[8];
#pragma unroll
    for (int mt = 0; mt < 8; mt++)
      af[mt] = *(const bf16x8*)(AH + (mt * 16 + l15) * LDA + c * 32 + quad * 8);
#pragma unroll
    for (int mt = 0; mt < 8; mt++) {
      acc[mt][0] = __builtin_amdgcn_mfma_f32_16x16x32_bf16(af[mt], wr[0][c], acc[mt][0], 0, 0, 0);
      acc[mt][1] = __builtin_amdgcn_mfma_f32_16x16x32_bf16(af[mt], wr[1][c], acc[mt][1], 0, 0, 0);
    }
  }

  // Epilogue B: waves 0-3 (j<128) -> tb bf16; waves 4-7 -> out fp32 + bias.
#pragma unroll
  for (int mt = 0; mt < 8; mt++) {
#pragma unroll
    for (int nt = 0; nt < 2; nt++) {
      const int j = wn + nt * 16 + l15;
      const float bv = nt ? cv1 : cv0;
#pragma unroll
      for (int r = 0; r < 4; r++) {
        const int node = m_blk + mt * 16 + quad * 4 + r;
        if (node >= M) continue;
        const float v = acc[mt][nt][r];
        if (j < 128) {
          tb[(size_t)node * 128 + j] = f2b(v);
        } else {
          out[(size_t)node * 128 + (j - 128)] = v + bv;
        }
      }
    }
  }
}

extern "C" void kernel_launch(void* const* d_in, const int* in_sizes, int n_in,
                              void* d_out, int out_size, void* d_ws, size_t ws_size,
                              hipStream_t stream) {
  const float* x   = (const float*)d_in[0];
  const int*  eidx = (const int*)d_in[1];
  const float* W1l = (const float*)d_in[2];
  const float* b1l = (const float*)d_in[3];
  const float* W1r = (const float*)d_in[4];
  const float* W2l = (const float*)d_in[5];
  const float* b2l = (const float*)d_in[6];
  const float* W2r = (const float*)d_in[7];
  float* out = (float*)d_out;

  const int N = in_sizes[0] / 128;
  const int E = in_sizes[1] / 2;
  const int* src = eidx;
  const int* dst = eidx + E;

  int* cnt  = (int*)d_ws;                       // [N] i32
  int* off  = cnt + N;                          // [N+1] i32
  int* bsum = off + N + 1;                      // [64] i32
  // u16 arrays: base rounded up to 16 B (R18 bug: was ≡4 mod 8 -> misaligned
  // ushort4 ops -> GPU fault). 2E bytes each; 2E % 16 == 0 keeps csr aligned.
  size_t cbase = (((size_t)(N + N + 1 + 64) * 4) + 15) & ~(size_t)15;
  unsigned short* rank = (unsigned short*)((char*)d_ws + cbase);  // [E] u16
  unsigned short* csr  = rank + E;                                // [E] u16
  size_t ioff = (cbase + (size_t)E * 4 + 15) & ~(size_t)15;
  unsigned short* A1  = (unsigned short*)((char*)d_ws + ioff);  // [N][256]
  unsigned short* tb  = A1 + (size_t)N * 256;                   // [N][128]
  unsigned short* Wc1 = tb + (size_t)N * 128;                   // [256][256]
  unsigned short* Wc2 = Wc1 + 65536;                            // [256][256]

  const int SB = (N + 1023) / 1024;  // 49

  prep_kernel<<<(N * 32 + 255) / 256, 256, 0, stream>>>(x, W1l, W1r, W2l, W2r,
                                                        Wc1, Wc2, A1, cnt, off, N, E);
  hist_kernel<<<(E / 4 + 255) / 256, 256, 0, stream>>>(dst, cnt, rank, E);
  scan_blocks_kernel<<<SB, 1024, 0, stream>>>(cnt, off, bsum, N);
  scan_add_kernel<<<SB, 1024, 0, stream>>>(off, bsum, N, SB);
  fill_kernel<<<(E / 4 + 255) / 256, 256, 0, stream>>>(src, dst, rank, off, csr, E);

  const int gblocks = (N + 3) / 4;  // 1 wave (64 lanes) per node
  gather1_kernel<<<gblocks, 256, 0, stream>>>(A1 + 128, csr, off, A1, N);

  gemm_fused<<<(N + 127) / 128, 512, 0, stream>>>(A1, Wc1, Wc2, b1l, b2l, tb, out, N);

  gather2_kernel<<<gblocks, 256, 0, stream>>>(tb, csr, off, out, N);
}